// Round 6
// baseline (3208.271 us; speedup 1.0000x reference)
//
#include <hip/hip_runtime.h>

// ---- problem dims ----
#define NN 20000
#define NE 640000
#define FF 128
#define H1 64
#define H2 32
#define RR 65
#define BQ 4096
#define NR (NN*RR)

// ---- small scratch block offsets (ints within sm[1024]) ----
#define SM_HIST_A 0
#define SM_START_A 128
#define SM_CUR_A 256
#define SM_HIST_B 384
#define SM_START_B 512
#define SM_CUR_B 640
#define SM_HACC 768   // 32 floats
#define SM_V 832      // 32 floats

#define CPB1 16       // blocks/relation, layer 1 (65*16=1040 ~ 4/CU, 32KB LDS)
#define CPB2 32       // layer 2 (65*32=2080, 8KB LDS)

// ===================== histogram =====================
__global__ __launch_bounds__(256) void k_hist(
    const int* __restrict__ ei, const int* __restrict__ etA, const int* __restrict__ etB,
    int* __restrict__ cntA, int* __restrict__ cntB, int* __restrict__ sm) {
  __shared__ int lh[2 * RR];
  int tid = threadIdx.x;
  for (int i = tid; i < 2 * RR; i += blockDim.x) lh[i] = 0;
  __syncthreads();
  int e = blockIdx.x * blockDim.x + tid;
  if (e < NE) {
    int dst = ei[NE + e];
    int ta = etA[e], tb = etB[e];
    atomicAdd(&cntA[dst * RR + ta], 1);
    atomicAdd(&cntB[dst * RR + tb], 1);
    atomicAdd(&lh[ta], 1);
    atomicAdd(&lh[RR + tb], 1);
  }
  __syncthreads();
  for (int i = tid; i < 2 * RR; i += blockDim.x) {
    int c = lh[i];
    if (c) atomicAdd(&sm[(i < RR) ? (SM_HIST_A + i) : (SM_HIST_B + (i - RR))], c);
  }
}

// ===================== exclusive prefix over 65 bins =====================
__global__ __launch_bounds__(128) void k_prefix(int* __restrict__ sm) {
  int w = threadIdx.x >> 6;
  if ((threadIdx.x & 63) == 0 && w < 2) {
    int hb = w ? SM_HIST_B : SM_HIST_A;
    int sb = w ? SM_START_B : SM_START_A;
    int cb = w ? SM_CUR_B : SM_CUR_A;
    int h[RR];
#pragma unroll
    for (int r = 0; r < RR; ++r) h[r] = sm[hb + r];
    int s = 0;
#pragma unroll
    for (int r = 0; r < RR; ++r) { sm[sb + r] = s; sm[cb + r] = s; s += h[r]; }
  }
}

// ===================== counting-sort scatter =====================
__global__ __launch_bounds__(256) void k_scatter(
    const int* __restrict__ etA, const int* __restrict__ etB,
    int* __restrict__ sm, int* __restrict__ ordA, int* __restrict__ ordB) {
  __shared__ int lhA[RR], lbA[RR], lhB[RR], lbB[RR];
  int tid = threadIdx.x;
  for (int i = tid; i < RR; i += blockDim.x) { lhA[i] = 0; lhB[i] = 0; }
  __syncthreads();
  int e = blockIdx.x * blockDim.x + tid;
  int ta = 0, tb = 0, ra = 0, rb = 0;
  bool valid = (e < NE);
  if (valid) {
    ta = etA[e]; tb = etB[e];
    ra = atomicAdd(&lhA[ta], 1);
    rb = atomicAdd(&lhB[tb], 1);
  }
  __syncthreads();
  for (int i = tid; i < RR; i += blockDim.x) {
    if (lhA[i]) lbA[i] = atomicAdd(&sm[SM_CUR_A + i], lhA[i]);
    if (lhB[i]) lbB[i] = atomicAdd(&sm[SM_CUR_B + i], lhB[i]);
  }
  __syncthreads();
  if (valid) { ordA[lbA[ta] + ra] = e; ordB[lbB[tb] + rb] = e; }
}

// ===================== counts -> 1/cnt =====================
__global__ __launch_bounds__(256) void k_inv(int* __restrict__ cntA, int* __restrict__ cntB) {
  int i = blockIdx.x * blockDim.x + threadIdx.x;
  if (i < NR) {
    int c = cntA[i]; ((float*)cntA)[i] = (c > 0) ? 1.0f / (float)c : 0.0f;
    c = cntB[i];     ((float*)cntB)[i] = (c > 0) ? 1.0f / (float)c : 0.0f;
  }
}

// ===================== flatten per-position edge meta: (src,dst) + inv ============
__global__ __launch_bounds__(256) void k_emeta(
    const int* __restrict__ ei, const int* __restrict__ ordA, const int* __restrict__ ordB,
    const float* __restrict__ invA, const float* __restrict__ invB,
    const int* __restrict__ etA, const int* __restrict__ etB,
    int2* __restrict__ sdA, float* __restrict__ ivA,
    int2* __restrict__ sdB, float* __restrict__ ivB) {
  int p = blockIdx.x * blockDim.x + threadIdx.x;
  if (p >= NE) return;
  {
    int e = ordA[p]; int s = ei[e], d = ei[NE + e]; int t = etA[e];
    sdA[p] = make_int2(s, d); ivA[p] = invA[(size_t)d * RR + t];
  }
  {
    int e = ordB[p]; int s = ei[e], d = ei[NE + e]; int t = etB[e];
    sdB[p] = make_int2(s, d); ivB[p] = invB[(size_t)d * RR + t];
  }
}

// ===================== layer-1 root term =====================
__global__ __launch_bounds__(256) void k_root1(
    const float* __restrict__ xo, const float* __restrict__ xa,
    const float* __restrict__ rt, const float* __restrict__ b,
    float* __restrict__ yo, float* __restrict__ yaa, float* __restrict__ ya) {
  int lane = threadIdx.x & 63;
  int n = (blockIdx.x * blockDim.x + threadIdx.x) >> 6;
  if (n >= NN) return;
  const float4* xo4 = (const float4*)(xo + (size_t)n * FF);
  const float4* xa4 = (const float4*)(xa + (size_t)n * FF);
  float so = b[lane], sa = so;
#pragma unroll
  for (int j = 0; j < FF / 4; ++j) {
    float vo[4], va[4];
    *(float4*)vo = xo4[j];
    *(float4*)va = xa4[j];
#pragma unroll
    for (int t = 0; t < 4; ++t) {
      float wv = rt[(4 * j + t) * H1 + lane];
      so = fmaf(vo[t], wv, so);
      sa = fmaf(va[t], wv, sa);
    }
  }
  yo[(size_t)n * H1 + lane] = so;
  yaa[(size_t)n * H1 + lane] = so;
  ya[(size_t)n * H1 + lane] = sa;
}

// ---- meta loader: single-level, fully-pipelineable loads ----
#define LOADMETA(P, S, D, V)                                        \
  {                                                                 \
    const int lim_ = cnt - (P) * EPG;                               \
    const int gb_ = s0 + (P) * EPG;                                 \
    _Pragma("unroll")                                               \
    for (int i_ = 0; i_ < EPG; ++i_) {                              \
      const int off_ = gb_ + ((i_ < lim_) ? i_ : 0);                \
      const int2 sd_ = sdp[off_];                                   \
      S[i_] = sd_.x; D[i_] = sd_.y;                                 \
      const float iv_ = invp[off_];                                 \
      V[i_] = (i_ < lim_) ? iv_ : 0.f;                              \
    }                                                               \
  }

// ===================== layer-1 edge transform+scatter ===============================
// W_r^T in LDS [o=64][chunk ^ (o&31)] (proven r3-r5). x chunks go global->register
// directly: wave-uniform address -> single L2 access broadcast on the VMEM return
// path (round-5 lesson: LDS broadcast reads cost a full 1024B slot per 16 useful
// bytes -> LDS-issue bound). Explicit 2-buffer ping-pong bounds live VGPRs (~120,
// no spill under the (256,2) cap) and issues loads a half-step ahead.
template <int NIN, int EPG>   // NIN*EPG == 8 rows/group
__global__ __launch_bounds__(256, 2) void k_edge1(
    const int2* __restrict__ sdp, const float* __restrict__ invp,
    const int* __restrict__ sm, int startOff, int histOff,
    const float* __restrict__ W1,
    const float* __restrict__ xA, const float* __restrict__ xB,
    float* __restrict__ yA, float* __restrict__ yB) {
  __shared__ __align__(16) float wlds[FF * H1];       // 32 KB
  const int r = blockIdx.x / CPB1;
  {
    const int o = threadIdx.x & 63;
    const int kb = (threadIdx.x >> 6) << 5;
    const float* Wr = W1 + (size_t)r * (FF * H1);
#pragma unroll
    for (int j = 0; j < 32; ++j) {
      const int k = kb + j;
      const int sc = (k >> 2) ^ (o & 31);
      wlds[o * 128 + sc * 4 + (k & 3)] = Wr[(size_t)k * H1 + o];
    }
  }
  __syncthreads();
  const int lane = threadIdx.x & 63;   // output column
  const int lx = lane & 31;
  const float* wrow = wlds + lane * 128;
  const int wvid = (blockIdx.x - r * CPB1) * 4 + (threadIdx.x >> 6);
  const int stride = CPB1 * 4;
  const int s0  = sm[startOff + r];
  const int cnt = sm[histOff + r];
  const int ngroups = (cnt + EPG - 1) / EPG;
  if (wvid >= ngroups) return;

  int srcC[EPG], dstC[EPG]; float invC[EPG];
  int srcN[EPG], dstN[EPG]; float invN[EPG];
  LOADMETA(wvid, srcC, dstC, invC);

  for (int G = wvid; G < ngroups; G += stride) {
    {
      const int Pn = (G + stride < ngroups) ? (G + stride) : G;
      LOADMETA(Pn, srcN, dstN, invN);   // hidden under this group's compute
    }
    const float* pr[8];
#pragma unroll
    for (int t = 0; t < 8; ++t) {
      if constexpr (NIN == 2) pr[t] = ((t & 1) ? xB : xA) + (size_t)srcC[t >> 1] * FF;
      else                    pr[t] = xA + (size_t)srcC[t] * FF;
    }
    float acc[8];
#pragma unroll
    for (int t = 0; t < 8; ++t) acc[t] = 0.f;
    float4 xe[8], xo_[8];
#pragma unroll
    for (int t = 0; t < 8; ++t) xe[t] = *(const float4*)(pr[t]);
#pragma unroll
    for (int c = 0; c < 32; c += 2) {
#pragma unroll
      for (int t = 0; t < 8; ++t) xo_[t] = *(const float4*)(pr[t] + ((c + 1) << 2));
      {
        const float4 w4 = *(const float4*)(wrow + ((c ^ lx) << 2));
#pragma unroll
        for (int t = 0; t < 8; ++t) {
          acc[t] = fmaf(xe[t].x, w4.x, acc[t]);
          acc[t] = fmaf(xe[t].y, w4.y, acc[t]);
          acc[t] = fmaf(xe[t].z, w4.z, acc[t]);
          acc[t] = fmaf(xe[t].w, w4.w, acc[t]);
        }
      }
      if (c + 2 < 32) {
#pragma unroll
        for (int t = 0; t < 8; ++t) xe[t] = *(const float4*)(pr[t] + ((c + 2) << 2));
      }
      {
        const float4 w4 = *(const float4*)(wrow + (((c + 1) ^ lx) << 2));
#pragma unroll
        for (int t = 0; t < 8; ++t) {
          acc[t] = fmaf(xo_[t].x, w4.x, acc[t]);
          acc[t] = fmaf(xo_[t].y, w4.y, acc[t]);
          acc[t] = fmaf(xo_[t].z, w4.z, acc[t]);
          acc[t] = fmaf(xo_[t].w, w4.w, acc[t]);
        }
      }
    }
#pragma unroll
    for (int t = 0; t < 8; ++t) {
      if constexpr (NIN == 2) {
        float* yp = (t & 1) ? yB : yA;
        unsafeAtomicAdd(&yp[(size_t)dstC[t >> 1] * H1 + lane], acc[t] * invC[t >> 1]);
      } else {
        unsafeAtomicAdd(&yA[(size_t)dstC[t] * H1 + lane], acc[t] * invC[t]);
      }
    }
#pragma unroll
    for (int i = 0; i < EPG; ++i) {
      srcC[i] = srcN[i]; dstC[i] = dstN[i]; invC[i] = invN[i];
    }
  }
}

// ===================== relu =====================
__global__ __launch_bounds__(256) void k_relu4(float4* __restrict__ a, int n4) {
  int i = blockIdx.x * blockDim.x + threadIdx.x;
  if (i < n4) {
    float4 v = a[i];
    v.x = fmaxf(v.x, 0.f); v.y = fmaxf(v.y, 0.f);
    v.z = fmaxf(v.z, 0.f); v.w = fmaxf(v.w, 0.f);
    a[i] = v;
  }
}

// ===================== layer-2 root term =====================
__global__ __launch_bounds__(256) void k_root2(
    const float* __restrict__ x1, const float* __restrict__ rt,
    const float* __restrict__ b, float* __restrict__ y) {
  int i = blockIdx.x * blockDim.x + threadIdx.x;
  if (i >= NN * H2) return;
  int o = i & (H2 - 1);
  int n = i >> 5;
  const float4* x4 = (const float4*)(x1 + (size_t)n * H1);
  float s = b[o];
#pragma unroll
  for (int j = 0; j < H1 / 4; ++j) {
    float v[4];
    *(float4*)v = x4[j];
#pragma unroll
    for (int t = 0; t < 4; ++t) s = fmaf(v[t], rt[(4 * j + t) * H2 + o], s);
  }
  y[i] = s;
}

// ===================== layer-2 edge transform+scatter ===============================
// Split-k: eh = lane>>5 covers 8 of 16 k-chunks; o = lane&31 output col; shfl_xor(32)
// combines. x direct global->reg, same ping-pong as k_edge1.
// Row layout rr=0..7: NIN==2: edge rr>>1, input rr&1 ; NIN==1: edge rr.
template <int NIN, int EPG>   // NIN*EPG == 8 rows/group
__global__ __launch_bounds__(256, 2) void k_edge2(
    const int2* __restrict__ sdp, const float* __restrict__ invp,
    const int* __restrict__ sm, int startOff, int histOff,
    const float* __restrict__ W2,
    const float* __restrict__ xA, const float* __restrict__ xB,
    float* __restrict__ yA, float* __restrict__ yB) {
  __shared__ __align__(16) float wlds[H1 * H2];       // 8 KB, [o=32][chunk ^ (o&15)]
  const int r = blockIdx.x / CPB2;
  {
    const int o = threadIdx.x & 31;
    const int kb = (threadIdx.x >> 5) << 3;
    const float* Wr = W2 + (size_t)r * (H1 * H2);
#pragma unroll
    for (int j = 0; j < 8; ++j) {
      const int k = kb + j;
      const int sc = (k >> 2) ^ (o & 15);
      wlds[o * 64 + sc * 4 + (k & 3)] = Wr[(size_t)k * H2 + o];
    }
  }
  __syncthreads();
  const int lane = threadIdx.x & 63;
  const int o  = lane & 31;
  const int eh = lane >> 5;
  const int ox = o & 15;
  const float* wrow = wlds + o * 64;
  const int wvid = (blockIdx.x - r * CPB2) * 4 + (threadIdx.x >> 6);
  const int stride = CPB2 * 4;
  const int s0  = sm[startOff + r];
  const int cnt = sm[histOff + r];
  const int ngroups = (cnt + EPG - 1) / EPG;
  if (wvid >= ngroups) return;

  int srcC[EPG], dstC[EPG]; float invC[EPG];
  int srcN[EPG], dstN[EPG]; float invN[EPG];
  LOADMETA(wvid, srcC, dstC, invC);

  for (int G = wvid; G < ngroups; G += stride) {
    {
      const int Pn = (G + stride < ngroups) ? (G + stride) : G;
      LOADMETA(Pn, srcN, dstN, invN);
    }
    const float* pr[8];
#pragma unroll
    for (int t = 0; t < 8; ++t) {
      if constexpr (NIN == 2) pr[t] = ((t & 1) ? xB : xA) + (size_t)srcC[t >> 1] * H1;
      else                    pr[t] = xA + (size_t)srcC[t] * H1;
    }
    float acc[8];
#pragma unroll
    for (int t = 0; t < 8; ++t) acc[t] = 0.f;
    float4 xe[8], xo_[8];
    const int ch0 = eh << 3;                         // this half's first k-chunk
#pragma unroll
    for (int t = 0; t < 8; ++t) xe[t] = *(const float4*)(pr[t] + (ch0 << 2));
#pragma unroll
    for (int c = 0; c < 8; c += 2) {
#pragma unroll
      for (int t = 0; t < 8; ++t) xo_[t] = *(const float4*)(pr[t] + ((ch0 + c + 1) << 2));
      {
        const float4 w4 = *(const float4*)(wrow + (((ch0 + c) ^ ox) << 2));
#pragma unroll
        for (int t = 0; t < 8; ++t) {
          acc[t] = fmaf(xe[t].x, w4.x, acc[t]);
          acc[t] = fmaf(xe[t].y, w4.y, acc[t]);
          acc[t] = fmaf(xe[t].z, w4.z, acc[t]);
          acc[t] = fmaf(xe[t].w, w4.w, acc[t]);
        }
      }
      if (c + 2 < 8) {
#pragma unroll
        for (int t = 0; t < 8; ++t) xe[t] = *(const float4*)(pr[t] + ((ch0 + c + 2) << 2));
      }
      {
        const float4 w4 = *(const float4*)(wrow + (((ch0 + c + 1) ^ ox) << 2));
#pragma unroll
        for (int t = 0; t < 8; ++t) {
          acc[t] = fmaf(xo_[t].x, w4.x, acc[t]);
          acc[t] = fmaf(xo_[t].y, w4.y, acc[t]);
          acc[t] = fmaf(xo_[t].z, w4.z, acc[t]);
          acc[t] = fmaf(xo_[t].w, w4.w, acc[t]);
        }
      }
    }
#pragma unroll
    for (int t = 0; t < 4; ++t) {
      float sa = acc[2 * t], sb = acc[2 * t + 1];
      sa += __shfl_xor(sa, 32);
      sb += __shfl_xor(sb, 32);
      if constexpr (NIN == 2) {
        const int d = dstC[t];
        const float vv = (eh ? sb : sa) * invC[t];
        float* yp = eh ? yB : yA;
        unsafeAtomicAdd(&yp[(size_t)d * H2 + o], vv);
      } else {
        const int d = eh ? dstC[2 * t + 1] : dstC[2 * t];
        const float vv = eh ? sb * invC[2 * t + 1] : sa * invC[2 * t];
        unsafeAtomicAdd(&yA[(size_t)d * H2 + o], vv);
      }
    }
#pragma unroll
    for (int i = 0; i < EPG; ++i) {
      srcC[i] = srcN[i]; dstC[i] = dstN[i]; invC[i] = invN[i];
    }
  }
}

// ===================== column sum of x2_o -> hacc[32] =====================
__global__ __launch_bounds__(256) void k_colsum(const float* __restrict__ x2o,
                                                float* __restrict__ hacc) {
  int tid = threadIdx.x;
  int col = tid & 31;
  int rgrp = blockIdx.x * (blockDim.x >> 5) + (tid >> 5);
  int nth = gridDim.x * (blockDim.x >> 5);
  float s = 0.f;
  for (int n = rgrp; n < NN; n += nth) s += x2o[(size_t)n * H2 + col];
  unsafeAtomicAdd(&hacc[col], s);
}

// ===================== h_os = sigmoid(mean); v = disc_w @ h_os =====================
__global__ __launch_bounds__(64) void k_disc(const float* __restrict__ hacc,
                                             const float* __restrict__ dw,
                                             float* __restrict__ vout) {
  __shared__ float hos[H2];
  int t = threadIdx.x;
  if (t < H2) hos[t] = 1.0f / (1.0f + expf(-hacc[t] / (float)NN));
  __syncthreads();
  if (t < H2) {
    float s = 0.f;
#pragma unroll
    for (int k = 0; k < H2; ++k) s = fmaf(dw[t * H2 + k], hos[k], s);
    vout[t] = s;
  }
}

// ===================== ret_os / ret_os_a =====================
__global__ __launch_bounds__(256) void k_ret(
    const float* __restrict__ x2o, const float* __restrict__ x2oa, const float* __restrict__ x2oaa,
    const float* __restrict__ v, const float* __restrict__ db,
    float* __restrict__ ros, float* __restrict__ rosa) {
  int n = blockIdx.x * blockDim.x + threadIdx.x;
  if (n >= NN) return;
  const float4* a4 = (const float4*)(x2o + (size_t)n * H2);
  const float4* b4 = (const float4*)(x2oa + (size_t)n * H2);
  const float4* c4 = (const float4*)(x2oaa + (size_t)n * H2);
  const float4* v4 = (const float4*)v;
  float r0 = 0.f, r1 = 0.f, r2 = 0.f;
#pragma unroll
  for (int j = 0; j < H2 / 4; ++j) {
    float va[4], vb[4], vc[4], vv[4];
    *(float4*)va = a4[j]; *(float4*)vb = b4[j]; *(float4*)vc = c4[j]; *(float4*)vv = v4[j];
#pragma unroll
    for (int t = 0; t < 4; ++t) {
      r0 = fmaf(va[t], vv[t], r0);
      r1 = fmaf(vb[t], vv[t], r1);
      r2 = fmaf(vc[t], vv[t], r2);
    }
  }
  float bb = db[0];
  ros[n * 2] = r0 + bb;  ros[n * 2 + 1] = r1 + bb;
  rosa[n * 2] = r0 + bb; rosa[n * 2 + 1] = r2 + bb;
}

// ===================== classifier =====================
__global__ __launch_bounds__(128) void k_cls(
    const int* __restrict__ idx, const float* __restrict__ x1o, const float* __restrict__ x2o,
    const float* __restrict__ attt, const float* __restrict__ cw, const float* __restrict__ cb,
    float* __restrict__ lg) {
  int b = blockIdx.x;
  int r = threadIdx.x;
  if (r >= RR) return;
  int i1 = idx[b], i2 = idx[BQ + b];
  float a0 = attt[0], a1 = attt[1];
  float acc = cb[r];
  const float4* q1 = (const float4*)(x1o + (size_t)i1 * H1);
  const float4* q2 = (const float4*)(x2o + (size_t)i1 * H2);
  const float4* q3 = (const float4*)(x1o + (size_t)i2 * H1);
  const float4* q4 = (const float4*)(x2o + (size_t)i2 * H2);
#pragma unroll
  for (int j = 0; j < H1 / 4; ++j) {
    float v[4]; *(float4*)v = q1[j];
#pragma unroll
    for (int t = 0; t < 4; ++t) acc = fmaf(a0 * v[t], cw[(4 * j + t) * RR + r], acc);
  }
#pragma unroll
  for (int j = 0; j < H2 / 4; ++j) {
    float v[4]; *(float4*)v = q2[j];
#pragma unroll
    for (int t = 0; t < 4; ++t) acc = fmaf(a1 * v[t], cw[(H1 + 4 * j + t) * RR + r], acc);
  }
#pragma unroll
  for (int j = 0; j < H1 / 4; ++j) {
    float v[4]; *(float4*)v = q3[j];
#pragma unroll
    for (int t = 0; t < 4; ++t) acc = fmaf(a0 * v[t], cw[(96 + 4 * j + t) * RR + r], acc);
  }
#pragma unroll
  for (int j = 0; j < H2 / 4; ++j) {
    float v[4]; *(float4*)v = q4[j];
#pragma unroll
    for (int t = 0; t < 4; ++t) acc = fmaf(a1 * v[t], cw[(96 + H1 + 4 * j + t) * RR + r], acc);
  }
  lg[(size_t)b * RR + r] = acc;
}

// ===================== launch =====================
extern "C" void kernel_launch(void* const* d_in, const int* in_sizes, int n_in,
                              void* d_out, int out_size, void* d_ws, size_t ws_size,
                              hipStream_t stream) {
  const float* x_o  = (const float*)d_in[0];
  const float* x_a  = (const float*)d_in[1];
  const int*   ei   = (const int*)d_in[2];
  const int*   etA  = (const int*)d_in[3];
  const int*   etB  = (const int*)d_in[4];
  const int*   idx  = (const int*)d_in[5];
  const float* W1   = (const float*)d_in[6];
  const float* rt1  = (const float*)d_in[7];
  const float* b1   = (const float*)d_in[8];
  const float* W2   = (const float*)d_in[9];
  const float* rt2  = (const float*)d_in[10];
  const float* b2   = (const float*)d_in[11];
  const float* attt = (const float*)d_in[12];
  const float* dw   = (const float*)d_in[13];
  const float* db   = (const float*)d_in[14];
  const float* cw   = (const float*)d_in[15];
  const float* cb   = (const float*)d_in[16];

  const size_t NRp = 1300224;
  int* wsI  = (int*)d_ws;
  int* cntA = wsI;                              // NRp -> float inv
  int* cntB = wsI + NRp;                        // NRp -> float inv
  int* sm   = wsI + 2 * NRp;                    // 1024
  int* ordA = sm + 1024;                        // NE
  int* ordB = ordA + NE;                        // NE
  int2*  sdA = (int2*)(ordB + NE);              // NE int2
  float* ivA = (float*)(sdA + NE);              // NE
  int2*  sdB = (int2*)(ivA + NE);               // NE int2
  float* ivB = (float*)(sdB + NE);              // NE
  float* x1o   = ivB + NE;                      // NN*H1 (x1o,x1a,x1aa contiguous for relu)
  float* x1a   = x1o + (size_t)NN * H1;
  float* x1aa  = x1a + (size_t)NN * H1;
  float* x2oa  = x1aa + (size_t)NN * H1;        // NN*H2
  float* x2oaa = x2oa + (size_t)NN * H2;        // NN*H2
  float* smF   = (float*)sm;
  float* hacc  = smF + SM_HACC;
  float* vbuf  = smF + SM_V;

  float* outF   = (float*)d_out;
  float* o_log  = outF;
  float* o_ros  = outF + (size_t)BQ * RR;
  float* o_rosa = o_ros + (size_t)NN * 2;
  float* o_x2o  = o_rosa + (size_t)NN * 2;

  hipMemsetAsync(wsI, 0, (2 * NRp + 1024) * sizeof(int), stream);

  k_hist<<<(NE + 255) / 256, 256, 0, stream>>>(ei, etA, etB, cntA, cntB, sm);
  k_prefix<<<1, 128, 0, stream>>>(sm);
  k_scatter<<<(NE + 255) / 256, 256, 0, stream>>>(etA, etB, sm, ordA, ordB);
  k_inv<<<(NR + 255) / 256, 256, 0, stream>>>(cntA, cntB);
  k_emeta<<<(NE + 255) / 256, 256, 0, stream>>>(ei, ordA, ordB,
                                                (const float*)cntA, (const float*)cntB,
                                                etA, etB, sdA, ivA, sdB, ivB);

  k_root1<<<(NN * H1) / 256, 256, 0, stream>>>(x_o, x_a, rt1, b1, x1o, x1aa, x1a);
  k_edge1<2, 4><<<RR * CPB1, 256, 0, stream>>>(sdA, ivA, sm, SM_START_A, SM_HIST_A,
                                               W1, x_o, x_a, x1o, x1a);
  k_edge1<1, 8><<<RR * CPB1, 256, 0, stream>>>(sdB, ivB, sm, SM_START_B, SM_HIST_B,
                                               W1, x_o, nullptr, x1aa, nullptr);
  k_relu4<<<(3 * NN * H1 / 4 + 255) / 256, 256, 0, stream>>>((float4*)x1o, 3 * NN * H1 / 4);

  k_root2<<<(NN * H2 + 255) / 256, 256, 0, stream>>>(x1o, rt2, b2, o_x2o);
  k_root2<<<(NN * H2 + 255) / 256, 256, 0, stream>>>(x1a, rt2, b2, x2oa);
  k_root2<<<(NN * H2 + 255) / 256, 256, 0, stream>>>(x1aa, rt2, b2, x2oaa);
  k_edge2<2, 4><<<RR * CPB2, 256, 0, stream>>>(sdA, ivA, sm, SM_START_A, SM_HIST_A,
                                               W2, x1o, x1a, o_x2o, x2oa);
  k_edge2<1, 8><<<RR * CPB2, 256, 0, stream>>>(sdB, ivB, sm, SM_START_B, SM_HIST_B,
                                               W2, x1aa, nullptr, x2oaa, nullptr);

  k_colsum<<<128, 256, 0, stream>>>(o_x2o, hacc);
  k_disc<<<1, 64, 0, stream>>>(hacc, dw, vbuf);
  k_ret<<<(NN + 255) / 256, 256, 0, stream>>>(o_x2o, x2oa, x2oaa, vbuf, db, o_ros, o_rosa);
  k_cls<<<BQ, 128, 0, stream>>>(idx, x1o, o_x2o, attt, cw, cb, o_log);
}

// Round 7
// 1058.534 us; speedup vs baseline: 3.0309x; 3.0309x over previous
//
#include <hip/hip_runtime.h>

// ---- problem dims ----
#define NN 20000
#define NE 640000
#define FF 128
#define H1 64
#define H2 32
#define RR 65
#define BQ 4096
#define NR (NN*RR)

// ---- small scratch block offsets (ints within sm[1024]) ----
#define SM_HIST_A 0
#define SM_START_A 128
#define SM_CUR_A 256
#define SM_HIST_B 384
#define SM_START_B 512
#define SM_CUR_B 640
#define SM_HACC 768   // 32 floats
#define SM_V 832      // 32 floats

#define CPB1 16       // blocks/relation for edge kernels (65*16=1040 blocks)
#define CPB2 16

typedef __attribute__((ext_vector_type(8))) short bhalf8;   // 8 bf16 (4 VGPRs)
typedef __attribute__((ext_vector_type(4))) float f32x4;
#define MFMA16(a, b, c) __builtin_amdgcn_mfma_f32_16x16x32_bf16(a, b, c, 0, 0, 0)

__device__ __forceinline__ unsigned short f2bf(float f) {
  unsigned int u = __float_as_uint(f);
  unsigned int r = (u + 0x7fffu + ((u >> 16) & 1u)) >> 16;   // RNE
  return (unsigned short)r;
}

// ===================== histogram =====================
__global__ __launch_bounds__(256) void k_hist(
    const int* __restrict__ ei, const int* __restrict__ etA, const int* __restrict__ etB,
    int* __restrict__ cntA, int* __restrict__ cntB, int* __restrict__ sm) {
  __shared__ int lh[2 * RR];
  int tid = threadIdx.x;
  for (int i = tid; i < 2 * RR; i += blockDim.x) lh[i] = 0;
  __syncthreads();
  int e = blockIdx.x * blockDim.x + tid;
  if (e < NE) {
    int dst = ei[NE + e];
    int ta = etA[e], tb = etB[e];
    atomicAdd(&cntA[dst * RR + ta], 1);
    atomicAdd(&cntB[dst * RR + tb], 1);
    atomicAdd(&lh[ta], 1);
    atomicAdd(&lh[RR + tb], 1);
  }
  __syncthreads();
  for (int i = tid; i < 2 * RR; i += blockDim.x) {
    int c = lh[i];
    if (c) atomicAdd(&sm[(i < RR) ? (SM_HIST_A + i) : (SM_HIST_B + (i - RR))], c);
  }
}

// ===================== exclusive prefix over 65 bins =====================
__global__ __launch_bounds__(128) void k_prefix(int* __restrict__ sm) {
  int w = threadIdx.x >> 6;
  if ((threadIdx.x & 63) == 0 && w < 2) {
    int hb = w ? SM_HIST_B : SM_HIST_A;
    int sb = w ? SM_START_B : SM_START_A;
    int cb = w ? SM_CUR_B : SM_CUR_A;
    int h[RR];
#pragma unroll
    for (int r = 0; r < RR; ++r) h[r] = sm[hb + r];
    int s = 0;
#pragma unroll
    for (int r = 0; r < RR; ++r) { sm[sb + r] = s; sm[cb + r] = s; s += h[r]; }
  }
}

// ===================== counting-sort scatter =====================
__global__ __launch_bounds__(256) void k_scatter(
    const int* __restrict__ etA, const int* __restrict__ etB,
    int* __restrict__ sm, int* __restrict__ ordA, int* __restrict__ ordB) {
  __shared__ int lhA[RR], lbA[RR], lhB[RR], lbB[RR];
  int tid = threadIdx.x;
  for (int i = tid; i < RR; i += blockDim.x) { lhA[i] = 0; lhB[i] = 0; }
  __syncthreads();
  int e = blockIdx.x * blockDim.x + tid;
  int ta = 0, tb = 0, ra = 0, rb = 0;
  bool valid = (e < NE);
  if (valid) {
    ta = etA[e]; tb = etB[e];
    ra = atomicAdd(&lhA[ta], 1);
    rb = atomicAdd(&lhB[tb], 1);
  }
  __syncthreads();
  for (int i = tid; i < RR; i += blockDim.x) {
    if (lhA[i]) lbA[i] = atomicAdd(&sm[SM_CUR_A + i], lhA[i]);
    if (lhB[i]) lbB[i] = atomicAdd(&sm[SM_CUR_B + i], lhB[i]);
  }
  __syncthreads();
  if (valid) { ordA[lbA[ta] + ra] = e; ordB[lbB[tb] + rb] = e; }
}

// ===================== counts -> 1/cnt =====================
__global__ __launch_bounds__(256) void k_inv(int* __restrict__ cntA, int* __restrict__ cntB) {
  int i = blockIdx.x * blockDim.x + threadIdx.x;
  if (i < NR) {
    int c = cntA[i]; ((float*)cntA)[i] = (c > 0) ? 1.0f / (float)c : 0.0f;
    c = cntB[i];     ((float*)cntB)[i] = (c > 0) ? 1.0f / (float)c : 0.0f;
  }
}

// ===================== flatten per-position edge meta =====================
__global__ __launch_bounds__(256) void k_emeta(
    const int* __restrict__ ei, const int* __restrict__ ordA, const int* __restrict__ ordB,
    const float* __restrict__ invA, const float* __restrict__ invB,
    const int* __restrict__ etA, const int* __restrict__ etB,
    int2* __restrict__ sdA, float* __restrict__ ivA,
    int2* __restrict__ sdB, float* __restrict__ ivB) {
  int p = blockIdx.x * blockDim.x + threadIdx.x;
  if (p >= NE) return;
  {
    int e = ordA[p]; int s = ei[e], d = ei[NE + e]; int t = etA[e];
    sdA[p] = make_int2(s, d); ivA[p] = invA[(size_t)d * RR + t];
  }
  {
    int e = ordB[p]; int s = ei[e], d = ei[NE + e]; int t = etB[e];
    sdB[p] = make_int2(s, d); ivB[p] = invB[(size_t)d * RR + t];
  }
}

// ===================== fp32 -> bf16 row conversion (8 elems/thread) ==============
__global__ __launch_bounds__(256) void k_cvt(const float4* __restrict__ in,
                                             uint4* __restrict__ out, int n8) {
  int i = blockIdx.x * blockDim.x + threadIdx.x;
  if (i >= n8) return;
  float4 a = in[2 * i], b = in[2 * i + 1];
  uint4 o;
  o.x = (unsigned)f2bf(a.x) | ((unsigned)f2bf(a.y) << 16);
  o.y = (unsigned)f2bf(a.z) | ((unsigned)f2bf(a.w) << 16);
  o.z = (unsigned)f2bf(b.x) | ((unsigned)f2bf(b.y) << 16);
  o.w = (unsigned)f2bf(b.z) | ((unsigned)f2bf(b.w) << 16);
  out[i] = o;
}

// ===================== relu in place (fp32) + bf16 copy =====================
__global__ __launch_bounds__(256) void k_relu_cvt(float* __restrict__ x,
                                                  uint4* __restrict__ x16, int n8) {
  int i = blockIdx.x * blockDim.x + threadIdx.x;
  if (i >= n8) return;
  float4* p = (float4*)x;
  float4 a = p[2 * i], b = p[2 * i + 1];
  a.x = fmaxf(a.x, 0.f); a.y = fmaxf(a.y, 0.f); a.z = fmaxf(a.z, 0.f); a.w = fmaxf(a.w, 0.f);
  b.x = fmaxf(b.x, 0.f); b.y = fmaxf(b.y, 0.f); b.z = fmaxf(b.z, 0.f); b.w = fmaxf(b.w, 0.f);
  p[2 * i] = a; p[2 * i + 1] = b;
  uint4 o;
  o.x = (unsigned)f2bf(a.x) | ((unsigned)f2bf(a.y) << 16);
  o.y = (unsigned)f2bf(a.z) | ((unsigned)f2bf(a.w) << 16);
  o.z = (unsigned)f2bf(b.x) | ((unsigned)f2bf(b.y) << 16);
  o.w = (unsigned)f2bf(b.z) | ((unsigned)f2bf(b.w) << 16);
  x16[i] = o;
}

// ===================== W1 -> bf16 B-fragments =====================
// Frag layout (16x16x32 bf16 B operand): lane l holds B[k=ks*32+(l>>4)*8+j][col=n*16+(l&15)].
// Flat: W1f[((r*16 + ks*4+n)*64 + lane)*8 + j]
__global__ __launch_bounds__(256) void k_wprep1(const float* __restrict__ W,
                                                unsigned short* __restrict__ Wf) {
  int r = blockIdx.x;
  int lane = threadIdx.x & 63, w = threadIdx.x >> 6;
#pragma unroll
  for (int s4 = 0; s4 < 4; ++s4) {
    int slot = w * 4 + s4;
    int ks = slot >> 2, n = slot & 3;
    int krow = ks * 32 + ((lane >> 4) << 3);
    int colo = n * 16 + (lane & 15);
    unsigned short* o = Wf + (((size_t)r * 16 + slot) * 64 + lane) * 8;
#pragma unroll
    for (int j = 0; j < 8; ++j)
      o[j] = f2bf(W[((size_t)r * FF + krow + j) * H1 + colo]);
  }
}

// ===================== W2 -> bf16 B-fragments (K=64, N=32 -> 4 slots/rel) ==========
__global__ __launch_bounds__(256) void k_wprep2(const float* __restrict__ W,
                                                unsigned short* __restrict__ Wf) {
  int r = blockIdx.x;
  int lane = threadIdx.x & 63, slot = threadIdx.x >> 6;   // 4 slots
  int ks = slot >> 1, n = slot & 1;
  int krow = ks * 32 + ((lane >> 4) << 3);
  int colo = n * 16 + (lane & 15);
  unsigned short* o = Wf + (((size_t)r * 4 + slot) * 64 + lane) * 8;
#pragma unroll
  for (int j = 0; j < 8; ++j)
    o[j] = f2bf(W[((size_t)r * H1 + krow + j) * H2 + colo]);
}

// ===================== layer-1 root term =====================
__global__ __launch_bounds__(256) void k_root1(
    const float* __restrict__ xo, const float* __restrict__ xa,
    const float* __restrict__ rt, const float* __restrict__ b,
    float* __restrict__ yo, float* __restrict__ yaa, float* __restrict__ ya) {
  int lane = threadIdx.x & 63;
  int n = (blockIdx.x * blockDim.x + threadIdx.x) >> 6;
  if (n >= NN) return;
  const float4* xo4 = (const float4*)(xo + (size_t)n * FF);
  const float4* xa4 = (const float4*)(xa + (size_t)n * FF);
  float so = b[lane], sa = so;
#pragma unroll
  for (int j = 0; j < FF / 4; ++j) {
    float vo[4], va[4];
    *(float4*)vo = xo4[j];
    *(float4*)va = xa4[j];
#pragma unroll
    for (int t = 0; t < 4; ++t) {
      float wv = rt[(4 * j + t) * H1 + lane];
      so = fmaf(vo[t], wv, so);
      sa = fmaf(va[t], wv, sa);
    }
  }
  yo[(size_t)n * H1 + lane] = so;
  yaa[(size_t)n * H1 + lane] = so;
  ya[(size_t)n * H1 + lane] = sa;
}

// ===================== layer-1 edge GEMM via MFMA ===============================
// Per wave-group: 16 edges. A-frag: lane l gathers 8 bf16 of row src(l&15) at
// k-slice (l>>4)*8 + ks*32 (each instr: 16 rows x 64B contiguous -> real per-lane
// VMEM parallelism, no broadcast waste). W_r B-frags: 16 x bhalf8 in 64 VGPRs.
// C/D layout (m89-verified): col=lane&15, row=(lane>>4)*4+reg. Scatter via shfl'd
// dst/inv + unsafeAtomicAdd (atomic count unchanged vs scalar version).
template <int NIN>
__global__ __launch_bounds__(256, 4) void k_edge1m(
    const int2* __restrict__ sdp, const float* __restrict__ invp,
    const int* __restrict__ sm, int startOff, int histOff,
    const unsigned short* __restrict__ Wf,
    const unsigned short* __restrict__ x16A, const unsigned short* __restrict__ x16B,
    float* __restrict__ yA, float* __restrict__ yB) {
  const int r = blockIdx.x / CPB1;
  const int lane = threadIdx.x & 63;
  bhalf8 wb[16];
  {
    const bhalf8* wf = (const bhalf8*)Wf + ((size_t)r * 16) * 64 + lane;
#pragma unroll
    for (int s = 0; s < 16; ++s) wb[s] = wf[(size_t)s * 64];
  }
  const int wvid = (blockIdx.x - r * CPB1) * 4 + (threadIdx.x >> 6);
  const int stride = CPB1 * 4;
  const int s0 = sm[startOff + r];
  const int cnt = sm[histOff + r];
  const int ngroups = (cnt + 15) >> 4;
  if (wvid >= ngroups) return;
  const int cg = lane >> 4;
  const int col = lane & 15;

  for (int G = wvid; G < ngroups; G += stride) {
    const int base = s0 + (G << 4);
    const int lim = cnt - (G << 4);
    const int off = base + ((col < lim) ? col : 0);
    const int2 sd = sdp[off];
    const float iv = (col < lim) ? invp[off] : 0.f;
    const int src = sd.x;
    const int dstv = sd.y;
    const int row0 = cg << 2;
    const int d0 = __shfl(dstv, row0),     d1 = __shfl(dstv, row0 + 1),
              d2 = __shfl(dstv, row0 + 2), d3 = __shfl(dstv, row0 + 3);
    const float i0 = __shfl(iv, row0),     i1 = __shfl(iv, row0 + 1),
                i2 = __shfl(iv, row0 + 2), i3 = __shfl(iv, row0 + 3);
    // ---- input A ----
    {
      const bhalf8* xr = (const bhalf8*)x16A + ((size_t)src << 4);
      bhalf8 a0 = xr[cg], a1 = xr[4 + cg], a2 = xr[8 + cg], a3 = xr[12 + cg];
      f32x4 c0 = {0.f,0.f,0.f,0.f}, c1 = c0, c2 = c0, c3 = c0;
      c0 = MFMA16(a0, wb[0], c0);  c1 = MFMA16(a0, wb[1], c1);
      c2 = MFMA16(a0, wb[2], c2);  c3 = MFMA16(a0, wb[3], c3);
      c0 = MFMA16(a1, wb[4], c0);  c1 = MFMA16(a1, wb[5], c1);
      c2 = MFMA16(a1, wb[6], c2);  c3 = MFMA16(a1, wb[7], c3);
      c0 = MFMA16(a2, wb[8], c0);  c1 = MFMA16(a2, wb[9], c1);
      c2 = MFMA16(a2, wb[10], c2); c3 = MFMA16(a2, wb[11], c3);
      c0 = MFMA16(a3, wb[12], c0); c1 = MFMA16(a3, wb[13], c1);
      c2 = MFMA16(a3, wb[14], c2); c3 = MFMA16(a3, wb[15], c3);
      const f32x4 cc[4] = {c0, c1, c2, c3};
#pragma unroll
      for (int n = 0; n < 4; ++n) {
        unsafeAtomicAdd(&yA[(size_t)d0 * H1 + n * 16 + col], cc[n][0] * i0);
        unsafeAtomicAdd(&yA[(size_t)d1 * H1 + n * 16 + col], cc[n][1] * i1);
        unsafeAtomicAdd(&yA[(size_t)d2 * H1 + n * 16 + col], cc[n][2] * i2);
        unsafeAtomicAdd(&yA[(size_t)d3 * H1 + n * 16 + col], cc[n][3] * i3);
      }
    }
    // ---- input B ----
    if constexpr (NIN == 2) {
      const bhalf8* xr = (const bhalf8*)x16B + ((size_t)src << 4);
      bhalf8 a0 = xr[cg], a1 = xr[4 + cg], a2 = xr[8 + cg], a3 = xr[12 + cg];
      f32x4 c0 = {0.f,0.f,0.f,0.f}, c1 = c0, c2 = c0, c3 = c0;
      c0 = MFMA16(a0, wb[0], c0);  c1 = MFMA16(a0, wb[1], c1);
      c2 = MFMA16(a0, wb[2], c2);  c3 = MFMA16(a0, wb[3], c3);
      c0 = MFMA16(a1, wb[4], c0);  c1 = MFMA16(a1, wb[5], c1);
      c2 = MFMA16(a1, wb[6], c2);  c3 = MFMA16(a1, wb[7], c3);
      c0 = MFMA16(a2, wb[8], c0);  c1 = MFMA16(a2, wb[9], c1);
      c2 = MFMA16(a2, wb[10], c2); c3 = MFMA16(a2, wb[11], c3);
      c0 = MFMA16(a3, wb[12], c0); c1 = MFMA16(a3, wb[13], c1);
      c2 = MFMA16(a3, wb[14], c2); c3 = MFMA16(a3, wb[15], c3);
      const f32x4 cc[4] = {c0, c1, c2, c3};
#pragma unroll
      for (int n = 0; n < 4; ++n) {
        unsafeAtomicAdd(&yB[(size_t)d0 * H1 + n * 16 + col], cc[n][0] * i0);
        unsafeAtomicAdd(&yB[(size_t)d1 * H1 + n * 16 + col], cc[n][1] * i1);
        unsafeAtomicAdd(&yB[(size_t)d2 * H1 + n * 16 + col], cc[n][2] * i2);
        unsafeAtomicAdd(&yB[(size_t)d3 * H1 + n * 16 + col], cc[n][3] * i3);
      }
    }
  }
}

// ===================== layer-2 root term =====================
__global__ __launch_bounds__(256) void k_root2(
    const float* __restrict__ x1, const float* __restrict__ rt,
    const float* __restrict__ b, float* __restrict__ y) {
  int i = blockIdx.x * blockDim.x + threadIdx.x;
  if (i >= NN * H2) return;
  int o = i & (H2 - 1);
  int n = i >> 5;
  const float4* x4 = (const float4*)(x1 + (size_t)n * H1);
  float s = b[o];
#pragma unroll
  for (int j = 0; j < H1 / 4; ++j) {
    float v[4];
    *(float4*)v = x4[j];
#pragma unroll
    for (int t = 0; t < 4; ++t) s = fmaf(v[t], rt[(4 * j + t) * H2 + o], s);
  }
  y[i] = s;
}

// ===================== layer-2 edge GEMM via MFMA (K=64, N=32) =====================
template <int NIN>
__global__ __launch_bounds__(256, 4) void k_edge2m(
    const int2* __restrict__ sdp, const float* __restrict__ invp,
    const int* __restrict__ sm, int startOff, int histOff,
    const unsigned short* __restrict__ Wf,
    const unsigned short* __restrict__ x16A, const unsigned short* __restrict__ x16B,
    float* __restrict__ yA, float* __restrict__ yB) {
  const int r = blockIdx.x / CPB2;
  const int lane = threadIdx.x & 63;
  bhalf8 wb[4];
  {
    const bhalf8* wf = (const bhalf8*)Wf + ((size_t)r * 4) * 64 + lane;
#pragma unroll
    for (int s = 0; s < 4; ++s) wb[s] = wf[(size_t)s * 64];
  }
  const int wvid = (blockIdx.x - r * CPB2) * 4 + (threadIdx.x >> 6);
  const int stride = CPB2 * 4;
  const int s0 = sm[startOff + r];
  const int cnt = sm[histOff + r];
  const int ngroups = (cnt + 15) >> 4;
  if (wvid >= ngroups) return;
  const int cg = lane >> 4;
  const int col = lane & 15;

  for (int G = wvid; G < ngroups; G += stride) {
    const int base = s0 + (G << 4);
    const int lim = cnt - (G << 4);
    const int off = base + ((col < lim) ? col : 0);
    const int2 sd = sdp[off];
    const float iv = (col < lim) ? invp[off] : 0.f;
    const int src = sd.x;
    const int dstv = sd.y;
    const int row0 = cg << 2;
    const int d0 = __shfl(dstv, row0),     d1 = __shfl(dstv, row0 + 1),
              d2 = __shfl(dstv, row0 + 2), d3 = __shfl(dstv, row0 + 3);
    const float i0 = __shfl(iv, row0),     i1 = __shfl(iv, row0 + 1),
                i2 = __shfl(iv, row0 + 2), i3 = __shfl(iv, row0 + 3);
    {
      const bhalf8* xr = (const bhalf8*)x16A + ((size_t)src << 3);
      bhalf8 a0 = xr[cg], a1 = xr[4 + cg];
      f32x4 c0 = {0.f,0.f,0.f,0.f}, c1 = c0;
      c0 = MFMA16(a0, wb[0], c0); c1 = MFMA16(a0, wb[1], c1);
      c0 = MFMA16(a1, wb[2], c0); c1 = MFMA16(a1, wb[3], c1);
      const f32x4 cc[2] = {c0, c1};
#pragma unroll
      for (int n = 0; n < 2; ++n) {
        unsafeAtomicAdd(&yA[(size_t)d0 * H2 + n * 16 + col], cc[n][0] * i0);
        unsafeAtomicAdd(&yA[(size_t)d1 * H2 + n * 16 + col], cc[n][1] * i1);
        unsafeAtomicAdd(&yA[(size_t)d2 * H2 + n * 16 + col], cc[n][2] * i2);
        unsafeAtomicAdd(&yA[(size_t)d3 * H2 + n * 16 + col], cc[n][3] * i3);
      }
    }
    if constexpr (NIN == 2) {
      const bhalf8* xr = (const bhalf8*)x16B + ((size_t)src << 3);
      bhalf8 a0 = xr[cg], a1 = xr[4 + cg];
      f32x4 c0 = {0.f,0.f,0.f,0.f}, c1 = c0;
      c0 = MFMA16(a0, wb[0], c0); c1 = MFMA16(a0, wb[1], c1);
      c0 = MFMA16(a1, wb[2], c0); c1 = MFMA16(a1, wb[3], c1);
      const f32x4 cc[2] = {c0, c1};
#pragma unroll
      for (int n = 0; n < 2; ++n) {
        unsafeAtomicAdd(&yB[(size_t)d0 * H2 + n * 16 + col], cc[n][0] * i0);
        unsafeAtomicAdd(&yB[(size_t)d1 * H2 + n * 16 + col], cc[n][1] * i1);
        unsafeAtomicAdd(&yB[(size_t)d2 * H2 + n * 16 + col], cc[n][2] * i2);
        unsafeAtomicAdd(&yB[(size_t)d3 * H2 + n * 16 + col], cc[n][3] * i3);
      }
    }
  }
}

// ===================== column sum of x2_o -> hacc[32] =====================
__global__ __launch_bounds__(256) void k_colsum(const float* __restrict__ x2o,
                                                float* __restrict__ hacc) {
  int tid = threadIdx.x;
  int col = tid & 31;
  int rgrp = blockIdx.x * (blockDim.x >> 5) + (tid >> 5);
  int nth = gridDim.x * (blockDim.x >> 5);
  float s = 0.f;
  for (int n = rgrp; n < NN; n += nth) s += x2o[(size_t)n * H2 + col];
  unsafeAtomicAdd(&hacc[col], s);
}

// ===================== h_os = sigmoid(mean); v = disc_w @ h_os =====================
__global__ __launch_bounds__(64) void k_disc(const float* __restrict__ hacc,
                                             const float* __restrict__ dw,
                                             float* __restrict__ vout) {
  __shared__ float hos[H2];
  int t = threadIdx.x;
  if (t < H2) hos[t] = 1.0f / (1.0f + expf(-hacc[t] / (float)NN));
  __syncthreads();
  if (t < H2) {
    float s = 0.f;
#pragma unroll
    for (int k = 0; k < H2; ++k) s = fmaf(dw[t * H2 + k], hos[k], s);
    vout[t] = s;
  }
}

// ===================== ret_os / ret_os_a =====================
__global__ __launch_bounds__(256) void k_ret(
    const float* __restrict__ x2o, const float* __restrict__ x2oa, const float* __restrict__ x2oaa,
    const float* __restrict__ v, const float* __restrict__ db,
    float* __restrict__ ros, float* __restrict__ rosa) {
  int n = blockIdx.x * blockDim.x + threadIdx.x;
  if (n >= NN) return;
  const float4* a4 = (const float4*)(x2o + (size_t)n * H2);
  const float4* b4 = (const float4*)(x2oa + (size_t)n * H2);
  const float4* c4 = (const float4*)(x2oaa + (size_t)n * H2);
  const float4* v4 = (const float4*)v;
  float r0 = 0.f, r1 = 0.f, r2 = 0.f;
#pragma unroll
  for (int j = 0; j < H2 / 4; ++j) {
    float va[4], vb[4], vc[4], vv[4];
    *(float4*)va = a4[j]; *(float4*)vb = b4[j]; *(float4*)vc = c4[j]; *(float4*)vv = v4[j];
#pragma unroll
    for (int t = 0; t < 4; ++t) {
      r0 = fmaf(va[t], vv[t], r0);
      r1 = fmaf(vb[t], vv[t], r1);
      r2 = fmaf(vc[t], vv[t], r2);
    }
  }
  float bb = db[0];
  ros[n * 2] = r0 + bb;  ros[n * 2 + 1] = r1 + bb;
  rosa[n * 2] = r0 + bb; rosa[n * 2 + 1] = r2 + bb;
}

// ===================== classifier =====================
__global__ __launch_bounds__(128) void k_cls(
    const int* __restrict__ idx, const float* __restrict__ x1o, const float* __restrict__ x2o,
    const float* __restrict__ attt, const float* __restrict__ cw, const float* __restrict__ cb,
    float* __restrict__ lg) {
  int b = blockIdx.x;
  int r = threadIdx.x;
  if (r >= RR) return;
  int i1 = idx[b], i2 = idx[BQ + b];
  float a0 = attt[0], a1 = attt[1];
  float acc = cb[r];
  const float4* q1 = (const float4*)(x1o + (size_t)i1 * H1);
  const float4* q2 = (const float4*)(x2o + (size_t)i1 * H2);
  const float4* q3 = (const float4*)(x1o + (size_t)i2 * H1);
  const float4* q4 = (const float4*)(x2o + (size_t)i2 * H2);
#pragma unroll
  for (int j = 0; j < H1 / 4; ++j) {
    float v[4]; *(float4*)v = q1[j];
#pragma unroll
    for (int t = 0; t < 4; ++t) acc = fmaf(a0 * v[t], cw[(4 * j + t) * RR + r], acc);
  }
#pragma unroll
  for (int j = 0; j < H2 / 4; ++j) {
    float v[4]; *(float4*)v = q2[j];
#pragma unroll
    for (int t = 0; t < 4; ++t) acc = fmaf(a1 * v[t], cw[(H1 + 4 * j + t) * RR + r], acc);
  }
#pragma unroll
  for (int j = 0; j < H1 / 4; ++j) {
    float v[4]; *(float4*)v = q3[j];
#pragma unroll
    for (int t = 0; t < 4; ++t) acc = fmaf(a0 * v[t], cw[(96 + 4 * j + t) * RR + r], acc);
  }
#pragma unroll
  for (int j = 0; j < H2 / 4; ++j) {
    float v[4]; *(float4*)v = q4[j];
#pragma unroll
    for (int t = 0; t < 4; ++t) acc = fmaf(a1 * v[t], cw[(96 + H1 + 4 * j + t) * RR + r], acc);
  }
  lg[(size_t)b * RR + r] = acc;
}

// ===================== launch =====================
extern "C" void kernel_launch(void* const* d_in, const int* in_sizes, int n_in,
                              void* d_out, int out_size, void* d_ws, size_t ws_size,
                              hipStream_t stream) {
  const float* x_o  = (const float*)d_in[0];
  const float* x_a  = (const float*)d_in[1];
  const int*   ei   = (const int*)d_in[2];
  const int*   etA  = (const int*)d_in[3];
  const int*   etB  = (const int*)d_in[4];
  const int*   idx  = (const int*)d_in[5];
  const float* W1   = (const float*)d_in[6];
  const float* rt1  = (const float*)d_in[7];
  const float* b1   = (const float*)d_in[8];
  const float* W2   = (const float*)d_in[9];
  const float* rt2  = (const float*)d_in[10];
  const float* b2   = (const float*)d_in[11];
  const float* attt = (const float*)d_in[12];
  const float* dw   = (const float*)d_in[13];
  const float* db   = (const float*)d_in[14];
  const float* cw   = (const float*)d_in[15];
  const float* cb   = (const float*)d_in[16];

  const size_t NRp = 1300224;
  int* wsI  = (int*)d_ws;
  int* cntA = wsI;                              // NRp -> float inv
  int* cntB = wsI + NRp;                        // NRp -> float inv
  int* sm   = wsI + 2 * NRp;                    // 1024
  int* ordA = sm + 1024;                        // NE
  int* ordB = ordA + NE;                        // NE
  int2*  sdA = (int2*)(ordB + NE);              // NE int2
  float* ivA = (float*)(sdA + NE);              // NE
  int2*  sdB = (int2*)(ivA + NE);               // NE int2
  float* ivB = (float*)(sdB + NE);              // NE
  float* x1o   = ivB + NE;                      // NN*H1 (x1o,x1a,x1aa contiguous)
  float* x1a   = x1o + (size_t)NN * H1;
  float* x1aa  = x1a + (size_t)NN * H1;
  float* x2oa  = x1aa + (size_t)NN * H1;        // NN*H2
  float* x2oaa = x2oa + (size_t)NN * H2;        // NN*H2
  unsigned int* xo16u = (unsigned int*)(x2oaa + (size_t)NN * H2);  // NN*FF/2 uints
  unsigned int* xa16u = xo16u + (size_t)NN * FF / 2;
  unsigned int* x116u = xa16u + (size_t)NN * FF / 2;               // 3*NN*H1/2 uints
  unsigned int* W1fu  = x116u + (size_t)3 * NN * H1 / 2;           // 266240 uints
  unsigned int* W2fu  = W1fu + 266240;                             // 66560 uints
  const unsigned short* xo16 = (const unsigned short*)xo16u;
  const unsigned short* xa16 = (const unsigned short*)xa16u;
  const unsigned short* x1o16  = (const unsigned short*)x116u;
  const unsigned short* x1a16  = x1o16 + (size_t)NN * H1;
  const unsigned short* x1aa16 = x1a16 + (size_t)NN * H1;
  unsigned short* W1f = (unsigned short*)W1fu;
  unsigned short* W2f = (unsigned short*)W2fu;
  float* smF   = (float*)sm;
  float* hacc  = smF + SM_HACC;
  float* vbuf  = smF + SM_V;

  float* outF   = (float*)d_out;
  float* o_log  = outF;
  float* o_ros  = outF + (size_t)BQ * RR;
  float* o_rosa = o_ros + (size_t)NN * 2;
  float* o_x2o  = o_rosa + (size_t)NN * 2;

  hipMemsetAsync(wsI, 0, (2 * NRp + 1024) * sizeof(int), stream);

  // prep: bf16 conversions + W fragment packing (independent of hist/sort chain)
  k_cvt<<<(NN * FF / 8 + 255) / 256, 256, 0, stream>>>((const float4*)x_o, (uint4*)xo16u, NN * FF / 8);
  k_cvt<<<(NN * FF / 8 + 255) / 256, 256, 0, stream>>>((const float4*)x_a, (uint4*)xa16u, NN * FF / 8);
  k_wprep1<<<RR, 256, 0, stream>>>(W1, W1f);
  k_wprep2<<<RR, 256, 0, stream>>>(W2, W2f);

  k_hist<<<(NE + 255) / 256, 256, 0, stream>>>(ei, etA, etB, cntA, cntB, sm);
  k_prefix<<<1, 128, 0, stream>>>(sm);
  k_scatter<<<(NE + 255) / 256, 256, 0, stream>>>(etA, etB, sm, ordA, ordB);
  k_inv<<<(NR + 255) / 256, 256, 0, stream>>>(cntA, cntB);
  k_emeta<<<(NE + 255) / 256, 256, 0, stream>>>(ei, ordA, ordB,
                                                (const float*)cntA, (const float*)cntB,
                                                etA, etB, sdA, ivA, sdB, ivB);

  k_root1<<<(NN * H1) / 256, 256, 0, stream>>>(x_o, x_a, rt1, b1, x1o, x1aa, x1a);
  k_edge1m<2><<<RR * CPB1, 256, 0, stream>>>(sdA, ivA, sm, SM_START_A, SM_HIST_A,
                                             W1f, xo16, xa16, x1o, x1a);
  k_edge1m<1><<<RR * CPB1, 256, 0, stream>>>(sdB, ivB, sm, SM_START_B, SM_HIST_B,
                                             W1f, xo16, nullptr, x1aa, nullptr);
  k_relu_cvt<<<(3 * NN * H1 / 8 + 255) / 256, 256, 0, stream>>>(x1o, (uint4*)x116u, 3 * NN * H1 / 8);

  k_root2<<<(NN * H2 + 255) / 256, 256, 0, stream>>>(x1o, rt2, b2, o_x2o);
  k_root2<<<(NN * H2 + 255) / 256, 256, 0, stream>>>(x1a, rt2, b2, x2oa);
  k_root2<<<(NN * H2 + 255) / 256, 256, 0, stream>>>(x1aa, rt2, b2, x2oaa);
  k_edge2m<2><<<RR * CPB2, 256, 0, stream>>>(sdA, ivA, sm, SM_START_A, SM_HIST_A,
                                             W2f, x1o16, x1a16, o_x2o, x2oa);
  k_edge2m<1><<<RR * CPB2, 256, 0, stream>>>(sdB, ivB, sm, SM_START_B, SM_HIST_B,
                                             W2f, x1aa16, nullptr, x2oaa, nullptr);

  k_colsum<<<128, 256, 0, stream>>>(o_x2o, hacc);
  k_disc<<<1, 64, 0, stream>>>(hacc, dw, vbuf);
  k_ret<<<(NN + 255) / 256, 256, 0, stream>>>(o_x2o, x2oa, x2oaa, vbuf, db, o_ros, o_rosa);
  k_cls<<<BQ, 128, 0, stream>>>(idx, x1o, o_x2o, attt, cw, cb, o_log);
}

// Round 8
// 1017.268 us; speedup vs baseline: 3.1538x; 1.0406x over previous
//
#include <hip/hip_runtime.h>

// ---- problem dims ----
#define NN 20000
#define NE 640000
#define FF 128
#define H1 64
#define H2 32
#define RR 65
#define BQ 4096
#define NR (NN*RR)

// ---- small scratch block offsets (ints within sm[1024]) ----
#define SM_HIST_A 0
#define SM_START_A 128
#define SM_CUR_A 256
#define SM_HIST_B 384
#define SM_START_B 512
#define SM_CUR_B 640
#define SM_HACC 768   // 32 floats
#define SM_V 832      // 32 floats

#define CPB1 32       // blocks/relation (65*32=2080 ~ 8.1/CU -> full wave occupancy)
#define CPB2 32

typedef __attribute__((ext_vector_type(8))) short bhalf8;   // 8 bf16 (4 VGPRs)
typedef __attribute__((ext_vector_type(4))) float f32x4;
#define MFMA16(a, b, c) __builtin_amdgcn_mfma_f32_16x16x32_bf16(a, b, c, 0, 0, 0)

__device__ __forceinline__ unsigned short f2bf(float f) {
  unsigned int u = __float_as_uint(f);
  unsigned int r = (u + 0x7fffu + ((u >> 16) & 1u)) >> 16;   // RNE
  return (unsigned short)r;
}

// ===================== histogram =====================
__global__ __launch_bounds__(256) void k_hist(
    const int* __restrict__ ei, const int* __restrict__ etA, const int* __restrict__ etB,
    int* __restrict__ cntA, int* __restrict__ cntB, int* __restrict__ sm) {
  __shared__ int lh[2 * RR];
  int tid = threadIdx.x;
  for (int i = tid; i < 2 * RR; i += blockDim.x) lh[i] = 0;
  __syncthreads();
  int e = blockIdx.x * blockDim.x + tid;
  if (e < NE) {
    int dst = ei[NE + e];
    int ta = etA[e], tb = etB[e];
    atomicAdd(&cntA[dst * RR + ta], 1);
    atomicAdd(&cntB[dst * RR + tb], 1);
    atomicAdd(&lh[ta], 1);
    atomicAdd(&lh[RR + tb], 1);
  }
  __syncthreads();
  for (int i = tid; i < 2 * RR; i += blockDim.x) {
    int c = lh[i];
    if (c) atomicAdd(&sm[(i < RR) ? (SM_HIST_A + i) : (SM_HIST_B + (i - RR))], c);
  }
}

// ===================== exclusive prefix over 65 bins =====================
__global__ __launch_bounds__(128) void k_prefix(int* __restrict__ sm) {
  int w = threadIdx.x >> 6;
  if ((threadIdx.x & 63) == 0 && w < 2) {
    int hb = w ? SM_HIST_B : SM_HIST_A;
    int sb = w ? SM_START_B : SM_START_A;
    int cb = w ? SM_CUR_B : SM_CUR_A;
    int h[RR];
#pragma unroll
    for (int r = 0; r < RR; ++r) h[r] = sm[hb + r];
    int s = 0;
#pragma unroll
    for (int r = 0; r < RR; ++r) { sm[sb + r] = s; sm[cb + r] = s; s += h[r]; }
  }
}

// ===================== counting-sort scatter =====================
__global__ __launch_bounds__(256) void k_scatter(
    const int* __restrict__ etA, const int* __restrict__ etB,
    int* __restrict__ sm, int* __restrict__ ordA, int* __restrict__ ordB) {
  __shared__ int lhA[RR], lbA[RR], lhB[RR], lbB[RR];
  int tid = threadIdx.x;
  for (int i = tid; i < RR; i += blockDim.x) { lhA[i] = 0; lhB[i] = 0; }
  __syncthreads();
  int e = blockIdx.x * blockDim.x + tid;
  int ta = 0, tb = 0, ra = 0, rb = 0;
  bool valid = (e < NE);
  if (valid) {
    ta = etA[e]; tb = etB[e];
    ra = atomicAdd(&lhA[ta], 1);
    rb = atomicAdd(&lhB[tb], 1);
  }
  __syncthreads();
  for (int i = tid; i < RR; i += blockDim.x) {
    if (lhA[i]) lbA[i] = atomicAdd(&sm[SM_CUR_A + i], lhA[i]);
    if (lhB[i]) lbB[i] = atomicAdd(&sm[SM_CUR_B + i], lhB[i]);
  }
  __syncthreads();
  if (valid) { ordA[lbA[ta] + ra] = e; ordB[lbB[tb] + rb] = e; }
}

// ===================== flatten per-position edge meta (inv computed inline) ========
__global__ __launch_bounds__(256) void k_emeta(
    const int* __restrict__ ei, const int* __restrict__ ordA, const int* __restrict__ ordB,
    const int* __restrict__ cntA, const int* __restrict__ cntB,
    const int* __restrict__ etA, const int* __restrict__ etB,
    int2* __restrict__ sdA, float* __restrict__ ivA,
    int2* __restrict__ sdB, float* __restrict__ ivB) {
  int p = blockIdx.x * blockDim.x + threadIdx.x;
  if (p >= NE) return;
  {
    int e = ordA[p]; int s = ei[e], d = ei[NE + e]; int t = etA[e];
    sdA[p] = make_int2(s, d);
    ivA[p] = 1.0f / (float)cntA[(size_t)d * RR + t];   // cnt>=1: this edge is in segment
  }
  {
    int e = ordB[p]; int s = ei[e], d = ei[NE + e]; int t = etB[e];
    sdB[p] = make_int2(s, d);
    ivB[p] = 1.0f / (float)cntB[(size_t)d * RR + t];
  }
}

// ===================== fp32 -> bf16 conversion for x_o and x_a in one pass ==========
__global__ __launch_bounds__(256) void k_cvt2(const float4* __restrict__ inA,
                                              const float4* __restrict__ inB,
                                              uint4* __restrict__ outA,
                                              uint4* __restrict__ outB, int n8) {
  int i = blockIdx.x * blockDim.x + threadIdx.x;
  if (i >= 2 * n8) return;
  const float4* in = (i < n8) ? inA : inB;
  uint4* out = (i < n8) ? outA : outB;
  int j = (i < n8) ? i : i - n8;
  float4 a = in[2 * j], b = in[2 * j + 1];
  uint4 o;
  o.x = (unsigned)f2bf(a.x) | ((unsigned)f2bf(a.y) << 16);
  o.y = (unsigned)f2bf(a.z) | ((unsigned)f2bf(a.w) << 16);
  o.z = (unsigned)f2bf(b.x) | ((unsigned)f2bf(b.y) << 16);
  o.w = (unsigned)f2bf(b.z) | ((unsigned)f2bf(b.w) << 16);
  out[j] = o;
}

// ===================== relu in place (fp32) + bf16 copy =====================
__global__ __launch_bounds__(256) void k_relu_cvt(float* __restrict__ x,
                                                  uint4* __restrict__ x16, int n8) {
  int i = blockIdx.x * blockDim.x + threadIdx.x;
  if (i >= n8) return;
  float4* p = (float4*)x;
  float4 a = p[2 * i], b = p[2 * i + 1];
  a.x = fmaxf(a.x, 0.f); a.y = fmaxf(a.y, 0.f); a.z = fmaxf(a.z, 0.f); a.w = fmaxf(a.w, 0.f);
  b.x = fmaxf(b.x, 0.f); b.y = fmaxf(b.y, 0.f); b.z = fmaxf(b.z, 0.f); b.w = fmaxf(b.w, 0.f);
  p[2 * i] = a; p[2 * i + 1] = b;
  uint4 o;
  o.x = (unsigned)f2bf(a.x) | ((unsigned)f2bf(a.y) << 16);
  o.y = (unsigned)f2bf(a.z) | ((unsigned)f2bf(a.w) << 16);
  o.z = (unsigned)f2bf(b.x) | ((unsigned)f2bf(b.y) << 16);
  o.w = (unsigned)f2bf(b.z) | ((unsigned)f2bf(b.w) << 16);
  x16[i] = o;
}

// ===================== W1 -> bf16 B-fragments =====================
// Frag layout (16x16x32 bf16 B operand): lane l holds B[k=ks*32+(l>>4)*8+j][col=n*16+(l&15)].
__global__ __launch_bounds__(256) void k_wprep1(const float* __restrict__ W,
                                                unsigned short* __restrict__ Wf) {
  int r = blockIdx.x;
  int lane = threadIdx.x & 63, w = threadIdx.x >> 6;
#pragma unroll
  for (int s4 = 0; s4 < 4; ++s4) {
    int slot = w * 4 + s4;
    int ks = slot >> 2, n = slot & 3;
    int krow = ks * 32 + ((lane >> 4) << 3);
    int colo = n * 16 + (lane & 15);
    unsigned short* o = Wf + (((size_t)r * 16 + slot) * 64 + lane) * 8;
#pragma unroll
    for (int j = 0; j < 8; ++j)
      o[j] = f2bf(W[((size_t)r * FF + krow + j) * H1 + colo]);
  }
}

// ===================== W2 -> bf16 B-fragments (K=64, N=32 -> 4 slots/rel) ==========
__global__ __launch_bounds__(256) void k_wprep2(const float* __restrict__ W,
                                                unsigned short* __restrict__ Wf) {
  int r = blockIdx.x;
  int lane = threadIdx.x & 63, slot = threadIdx.x >> 6;   // 4 slots
  int ks = slot >> 1, n = slot & 1;
  int krow = ks * 32 + ((lane >> 4) << 3);
  int colo = n * 16 + (lane & 15);
  unsigned short* o = Wf + (((size_t)r * 4 + slot) * 64 + lane) * 8;
#pragma unroll
  for (int j = 0; j < 8; ++j)
    o[j] = f2bf(W[((size_t)r * H1 + krow + j) * H2 + colo]);
}

// ===================== layer-1 root term =====================
__global__ __launch_bounds__(256) void k_root1(
    const float* __restrict__ xo, const float* __restrict__ xa,
    const float* __restrict__ rt, const float* __restrict__ b,
    float* __restrict__ yo, float* __restrict__ yaa, float* __restrict__ ya) {
  int lane = threadIdx.x & 63;
  int n = (blockIdx.x * blockDim.x + threadIdx.x) >> 6;
  if (n >= NN) return;
  const float4* xo4 = (const float4*)(xo + (size_t)n * FF);
  const float4* xa4 = (const float4*)(xa + (size_t)n * FF);
  float so = b[lane], sa = so;
#pragma unroll
  for (int j = 0; j < FF / 4; ++j) {
    float vo[4], va[4];
    *(float4*)vo = xo4[j];
    *(float4*)va = xa4[j];
#pragma unroll
    for (int t = 0; t < 4; ++t) {
      float wv = rt[(4 * j + t) * H1 + lane];
      so = fmaf(vo[t], wv, so);
      sa = fmaf(va[t], wv, sa);
    }
  }
  yo[(size_t)n * H1 + lane] = so;
  yaa[(size_t)n * H1 + lane] = so;
  ya[(size_t)n * H1 + lane] = sa;
}

// ===================== layer-1 edge GEMM via MFMA ===============================
// 16 edges/wave-group; W_r B-frags resident in 64 VGPRs; next-group meta
// prefetched one iteration ahead (removes a memory round-trip from the serial
// chain: x-gather addresses are ready the moment a group starts).
template <int NIN>
__global__ __launch_bounds__(256, 4) void k_edge1m(
    const int2* __restrict__ sdp, const float* __restrict__ invp,
    const int* __restrict__ sm, int startOff, int histOff,
    const unsigned short* __restrict__ Wf,
    const unsigned short* __restrict__ x16A, const unsigned short* __restrict__ x16B,
    float* __restrict__ yA, float* __restrict__ yB) {
  const int r = blockIdx.x / CPB1;
  const int lane = threadIdx.x & 63;
  bhalf8 wb[16];
  {
    const bhalf8* wf = (const bhalf8*)Wf + ((size_t)r * 16) * 64 + lane;
#pragma unroll
    for (int s = 0; s < 16; ++s) wb[s] = wf[(size_t)s * 64];
  }
  const int wvid = (blockIdx.x - r * CPB1) * 4 + (threadIdx.x >> 6);
  const int stride = CPB1 * 4;
  const int s0 = sm[startOff + r];
  const int cnt = sm[histOff + r];
  const int ngroups = (cnt + 15) >> 4;
  if (wvid >= ngroups) return;
  const int cg = lane >> 4;
  const int col = lane & 15;

  int2 sdC; float ivC;
  {
    const int base = s0 + (wvid << 4);
    const int lim = cnt - (wvid << 4);
    const int off = base + ((col < lim) ? col : 0);
    sdC = sdp[off];
    ivC = (col < lim) ? invp[off] : 0.f;
  }
  for (int G = wvid; G < ngroups; G += stride) {
    const int Gn = G + stride;
    int2 sdN = sdC; float ivN = ivC;
    if (Gn < ngroups) {                      // prefetch next group's meta
      const int base = s0 + (Gn << 4);
      const int lim = cnt - (Gn << 4);
      const int off = base + ((col < lim) ? col : 0);
      sdN = sdp[off];
      ivN = (col < lim) ? invp[off] : 0.f;
    }
    const int src = sdC.x;
    const int dstv = sdC.y;
    const int row0 = cg << 2;
    const int d0 = __shfl(dstv, row0),     d1 = __shfl(dstv, row0 + 1),
              d2 = __shfl(dstv, row0 + 2), d3 = __shfl(dstv, row0 + 3);
    const float i0 = __shfl(ivC, row0),     i1 = __shfl(ivC, row0 + 1),
                i2 = __shfl(ivC, row0 + 2), i3 = __shfl(ivC, row0 + 3);
    // ---- input A ----
    {
      const bhalf8* xr = (const bhalf8*)x16A + ((size_t)src << 4);
      bhalf8 a0 = xr[cg], a1 = xr[4 + cg], a2 = xr[8 + cg], a3 = xr[12 + cg];
      f32x4 c0 = {0.f,0.f,0.f,0.f}, c1 = c0, c2 = c0, c3 = c0;
      c0 = MFMA16(a0, wb[0], c0);  c1 = MFMA16(a0, wb[1], c1);
      c2 = MFMA16(a0, wb[2], c2);  c3 = MFMA16(a0, wb[3], c3);
      c0 = MFMA16(a1, wb[4], c0);  c1 = MFMA16(a1, wb[5], c1);
      c2 = MFMA16(a1, wb[6], c2);  c3 = MFMA16(a1, wb[7], c3);
      c0 = MFMA16(a2, wb[8], c0);  c1 = MFMA16(a2, wb[9], c1);
      c2 = MFMA16(a2, wb[10], c2); c3 = MFMA16(a2, wb[11], c3);
      c0 = MFMA16(a3, wb[12], c0); c1 = MFMA16(a3, wb[13], c1);
      c2 = MFMA16(a3, wb[14], c2); c3 = MFMA16(a3, wb[15], c3);
      const f32x4 cc[4] = {c0, c1, c2, c3};
#pragma unroll
      for (int n = 0; n < 4; ++n) {
        unsafeAtomicAdd(&yA[(size_t)d0 * H1 + n * 16 + col], cc[n][0] * i0);
        unsafeAtomicAdd(&yA[(size_t)d1 * H1 + n * 16 + col], cc[n][1] * i1);
        unsafeAtomicAdd(&yA[(size_t)d2 * H1 + n * 16 + col], cc[n][2] * i2);
        unsafeAtomicAdd(&yA[(size_t)d3 * H1 + n * 16 + col], cc[n][3] * i3);
      }
    }
    // ---- input B ----
    if constexpr (NIN == 2) {
      const bhalf8* xr = (const bhalf8*)x16B + ((size_t)src << 4);
      bhalf8 a0 = xr[cg], a1 = xr[4 + cg], a2 = xr[8 + cg], a3 = xr[12 + cg];
      f32x4 c0 = {0.f,0.f,0.f,0.f}, c1 = c0, c2 = c0, c3 = c0;
      c0 = MFMA16(a0, wb[0], c0);  c1 = MFMA16(a0, wb[1], c1);
      c2 = MFMA16(a0, wb[2], c2);  c3 = MFMA16(a0, wb[3], c3);
      c0 = MFMA16(a1, wb[4], c0);  c1 = MFMA16(a1, wb[5], c1);
      c2 = MFMA16(a1, wb[6], c2);  c3 = MFMA16(a1, wb[7], c3);
      c0 = MFMA16(a2, wb[8], c0);  c1 = MFMA16(a2, wb[9], c1);
      c2 = MFMA16(a2, wb[10], c2); c3 = MFMA16(a2, wb[11], c3);
      c0 = MFMA16(a3, wb[12], c0); c1 = MFMA16(a3, wb[13], c1);
      c2 = MFMA16(a3, wb[14], c2); c3 = MFMA16(a3, wb[15], c3);
      const f32x4 cc[4] = {c0, c1, c2, c3};
#pragma unroll
      for (int n = 0; n < 4; ++n) {
        unsafeAtomicAdd(&yB[(size_t)d0 * H1 + n * 16 + col], cc[n][0] * i0);
        unsafeAtomicAdd(&yB[(size_t)d1 * H1 + n * 16 + col], cc[n][1] * i1);
        unsafeAtomicAdd(&yB[(size_t)d2 * H1 + n * 16 + col], cc[n][2] * i2);
        unsafeAtomicAdd(&yB[(size_t)d3 * H1 + n * 16 + col], cc[n][3] * i3);
      }
    }
    sdC = sdN; ivC = ivN;
  }
}

// ===================== layer-2 root term, all three passes fused =====================
__global__ __launch_bounds__(256) void k_root2x3(
    const float* __restrict__ x1o, const float* __restrict__ x1a, const float* __restrict__ x1aa,
    const float* __restrict__ rt, const float* __restrict__ b,
    float* __restrict__ y0, float* __restrict__ y1, float* __restrict__ y2) {
  int i = blockIdx.x * blockDim.x + threadIdx.x;
  if (i >= NN * H2) return;
  int o = i & (H2 - 1);
  int n = i >> 5;
  const float4* p0 = (const float4*)(x1o + (size_t)n * H1);
  const float4* p1 = (const float4*)(x1a + (size_t)n * H1);
  const float4* p2 = (const float4*)(x1aa + (size_t)n * H1);
  float s0 = b[o], s1 = s0, s2 = s0;
#pragma unroll
  for (int j = 0; j < H1 / 4; ++j) {
    float v0[4], v1[4], v2[4];
    *(float4*)v0 = p0[j]; *(float4*)v1 = p1[j]; *(float4*)v2 = p2[j];
#pragma unroll
    for (int t = 0; t < 4; ++t) {
      float wv = rt[(4 * j + t) * H2 + o];
      s0 = fmaf(v0[t], wv, s0);
      s1 = fmaf(v1[t], wv, s1);
      s2 = fmaf(v2[t], wv, s2);
    }
  }
  y0[i] = s0; y1[i] = s1; y2[i] = s2;
}

// ===================== layer-2 edge GEMM via MFMA (K=64, N=32) =====================
template <int NIN>
__global__ __launch_bounds__(256, 4) void k_edge2m(
    const int2* __restrict__ sdp, const float* __restrict__ invp,
    const int* __restrict__ sm, int startOff, int histOff,
    const unsigned short* __restrict__ Wf,
    const unsigned short* __restrict__ x16A, const unsigned short* __restrict__ x16B,
    float* __restrict__ yA, float* __restrict__ yB) {
  const int r = blockIdx.x / CPB2;
  const int lane = threadIdx.x & 63;
  bhalf8 wb[4];
  {
    const bhalf8* wf = (const bhalf8*)Wf + ((size_t)r * 4) * 64 + lane;
#pragma unroll
    for (int s = 0; s < 4; ++s) wb[s] = wf[(size_t)s * 64];
  }
  const int wvid = (blockIdx.x - r * CPB2) * 4 + (threadIdx.x >> 6);
  const int stride = CPB2 * 4;
  const int s0 = sm[startOff + r];
  const int cnt = sm[histOff + r];
  const int ngroups = (cnt + 15) >> 4;
  if (wvid >= ngroups) return;
  const int cg = lane >> 4;
  const int col = lane & 15;

  int2 sdC; float ivC;
  {
    const int base = s0 + (wvid << 4);
    const int lim = cnt - (wvid << 4);
    const int off = base + ((col < lim) ? col : 0);
    sdC = sdp[off];
    ivC = (col < lim) ? invp[off] : 0.f;
  }
  for (int G = wvid; G < ngroups; G += stride) {
    const int Gn = G + stride;
    int2 sdN = sdC; float ivN = ivC;
    if (Gn < ngroups) {
      const int base = s0 + (Gn << 4);
      const int lim = cnt - (Gn << 4);
      const int off = base + ((col < lim) ? col : 0);
      sdN = sdp[off];
      ivN = (col < lim) ? invp[off] : 0.f;
    }
    const int src = sdC.x;
    const int dstv = sdC.y;
    const int row0 = cg << 2;
    const int d0 = __shfl(dstv, row0),     d1 = __shfl(dstv, row0 + 1),
              d2 = __shfl(dstv, row0 + 2), d3 = __shfl(dstv, row0 + 3);
    const float i0 = __shfl(ivC, row0),     i1 = __shfl(ivC, row0 + 1),
                i2 = __shfl(ivC, row0 + 2), i3 = __shfl(ivC, row0 + 3);
    {
      const bhalf8* xr = (const bhalf8*)x16A + ((size_t)src << 3);
      bhalf8 a0 = xr[cg], a1 = xr[4 + cg];
      f32x4 c0 = {0.f,0.f,0.f,0.f}, c1 = c0;
      c0 = MFMA16(a0, wb[0], c0); c1 = MFMA16(a0, wb[1], c1);
      c0 = MFMA16(a1, wb[2], c0); c1 = MFMA16(a1, wb[3], c1);
      const f32x4 cc[2] = {c0, c1};
#pragma unroll
      for (int n = 0; n < 2; ++n) {
        unsafeAtomicAdd(&yA[(size_t)d0 * H2 + n * 16 + col], cc[n][0] * i0);
        unsafeAtomicAdd(&yA[(size_t)d1 * H2 + n * 16 + col], cc[n][1] * i1);
        unsafeAtomicAdd(&yA[(size_t)d2 * H2 + n * 16 + col], cc[n][2] * i2);
        unsafeAtomicAdd(&yA[(size_t)d3 * H2 + n * 16 + col], cc[n][3] * i3);
      }
    }
    if constexpr (NIN == 2) {
      const bhalf8* xr = (const bhalf8*)x16B + ((size_t)src << 3);
      bhalf8 a0 = xr[cg], a1 = xr[4 + cg];
      f32x4 c0 = {0.f,0.f,0.f,0.f}, c1 = c0;
      c0 = MFMA16(a0, wb[0], c0); c1 = MFMA16(a0, wb[1], c1);
      c0 = MFMA16(a1, wb[2], c0); c1 = MFMA16(a1, wb[3], c1);
      const f32x4 cc[2] = {c0, c1};
#pragma unroll
      for (int n = 0; n < 2; ++n) {
        unsafeAtomicAdd(&yB[(size_t)d0 * H2 + n * 16 + col], cc[n][0] * i0);
        unsafeAtomicAdd(&yB[(size_t)d1 * H2 + n * 16 + col], cc[n][1] * i1);
        unsafeAtomicAdd(&yB[(size_t)d2 * H2 + n * 16 + col], cc[n][2] * i2);
        unsafeAtomicAdd(&yB[(size_t)d3 * H2 + n * 16 + col], cc[n][3] * i3);
      }
    }
    sdC = sdN; ivC = ivN;
  }
}

// ===================== column sum of x2_o -> hacc[32] =====================
__global__ __launch_bounds__(256) void k_colsum(const float* __restrict__ x2o,
                                                float* __restrict__ hacc) {
  int tid = threadIdx.x;
  int col = tid & 31;
  int rgrp = blockIdx.x * (blockDim.x >> 5) + (tid >> 5);
  int nth = gridDim.x * (blockDim.x >> 5);
  float s = 0.f;
  for (int n = rgrp; n < NN; n += nth) s += x2o[(size_t)n * H2 + col];
  unsafeAtomicAdd(&hacc[col], s);
}

// ===================== h_os = sigmoid(mean); v = disc_w @ h_os =====================
__global__ __launch_bounds__(64) void k_disc(const float* __restrict__ hacc,
                                             const float* __restrict__ dw,
                                             float* __restrict__ vout) {
  __shared__ float hos[H2];
  int t = threadIdx.x;
  if (t < H2) hos[t] = 1.0f / (1.0f + expf(-hacc[t] / (float)NN));
  __syncthreads();
  if (t < H2) {
    float s = 0.f;
#pragma unroll
    for (int k = 0; k < H2; ++k) s = fmaf(dw[t * H2 + k], hos[k], s);
    vout[t] = s;
  }
}

// ===================== ret_os / ret_os_a =====================
__global__ __launch_bounds__(256) void k_ret(
    const float* __restrict__ x2o, const float* __restrict__ x2oa, const float* __restrict__ x2oaa,
    const float* __restrict__ v, const float* __restrict__ db,
    float* __restrict__ ros, float* __restrict__ rosa) {
  int n = blockIdx.x * blockDim.x + threadIdx.x;
  if (n >= NN) return;
  const float4* a4 = (const float4*)(x2o + (size_t)n * H2);
  const float4* b4 = (const float4*)(x2oa + (size_t)n * H2);
  const float4* c4 = (const float4*)(x2oaa + (size_t)n * H2);
  const float4* v4 = (const float4*)v;
  float r0 = 0.f, r1 = 0.f, r2 = 0.f;
#pragma unroll
  for (int j = 0; j < H2 / 4; ++j) {
    float va[4], vb[4], vc[4], vv[4];
    *(float4*)va = a4[j]; *(float4*)vb = b4[j]; *(float4*)vc = c4[j]; *(float4*)vv = v4[j];
#pragma unroll
    for (int t = 0; t < 4; ++t) {
      r0 = fmaf(va[t], vv[t], r0);
      r1 = fmaf(vb[t], vv[t], r1);
      r2 = fmaf(vc[t], vv[t], r2);
    }
  }
  float bb = db[0];
  ros[n * 2] = r0 + bb;  ros[n * 2 + 1] = r1 + bb;
  rosa[n * 2] = r0 + bb; rosa[n * 2 + 1] = r2 + bb;
}

// ===================== classifier =====================
__global__ __launch_bounds__(128) void k_cls(
    const int* __restrict__ idx, const float* __restrict__ x1o, const float* __restrict__ x2o,
    const float* __restrict__ attt, const float* __restrict__ cw, const float* __restrict__ cb,
    float* __restrict__ lg) {
  int b = blockIdx.x;
  int r = threadIdx.x;
  if (r >= RR) return;
  int i1 = idx[b], i2 = idx[BQ + b];
  float a0 = attt[0], a1 = attt[1];
  float acc = cb[r];
  const float4* q1 = (const float4*)(x1o + (size_t)i1 * H1);
  const float4* q2 = (const float4*)(x2o + (size_t)i1 * H2);
  const float4* q3 = (const float4*)(x1o + (size_t)i2 * H1);
  const float4* q4 = (const float4*)(x2o + (size_t)i2 * H2);
#pragma unroll
  for (int j = 0; j < H1 / 4; ++j) {
    float v[4]; *(float4*)v = q1[j];
#pragma unroll
    for (int t = 0; t < 4; ++t) acc = fmaf(a0 * v[t], cw[(4 * j + t) * RR + r], acc);
  }
#pragma unroll
  for (int j = 0; j < H2 / 4; ++j) {
    float v[4]; *(float4*)v = q2[j];
#pragma unroll
    for (int t = 0; t < 4; ++t) acc = fmaf(a1 * v[t], cw[(H1 + 4 * j + t) * RR + r], acc);
  }
#pragma unroll
  for (int j = 0; j < H1 / 4; ++j) {
    float v[4]; *(float4*)v = q3[j];
#pragma unroll
    for (int t = 0; t < 4; ++t) acc = fmaf(a0 * v[t], cw[(96 + 4 * j + t) * RR + r], acc);
  }
#pragma unroll
  for (int j = 0; j < H2 / 4; ++j) {
    float v[4]; *(float4*)v = q4[j];
#pragma unroll
    for (int t = 0; t < 4; ++t) acc = fmaf(a1 * v[t], cw[(96 + H1 + 4 * j + t) * RR + r], acc);
  }
  lg[(size_t)b * RR + r] = acc;
}

// ===================== launch =====================
extern "C" void kernel_launch(void* const* d_in, const int* in_sizes, int n_in,
                              void* d_out, int out_size, void* d_ws, size_t ws_size,
                              hipStream_t stream) {
  const float* x_o  = (const float*)d_in[0];
  const float* x_a  = (const float*)d_in[1];
  const int*   ei   = (const int*)d_in[2];
  const int*   etA  = (const int*)d_in[3];
  const int*   etB  = (const int*)d_in[4];
  const int*   idx  = (const int*)d_in[5];
  const float* W1   = (const float*)d_in[6];
  const float* rt1  = (const float*)d_in[7];
  const float* b1   = (const float*)d_in[8];
  const float* W2   = (const float*)d_in[9];
  const float* rt2  = (const float*)d_in[10];
  const float* b2   = (const float*)d_in[11];
  const float* attt = (const float*)d_in[12];
  const float* dw   = (const float*)d_in[13];
  const float* db   = (const float*)d_in[14];
  const float* cw   = (const float*)d_in[15];
  const float* cb   = (const float*)d_in[16];

  const size_t NRp = 1300224;
  int* wsI  = (int*)d_ws;
  int* cntA = wsI;                              // NRp ints
  int* cntB = wsI + NRp;                        // NRp ints
  int* sm   = wsI + 2 * NRp;                    // 1024
  int* ordA = sm + 1024;                        // NE
  int* ordB = ordA + NE;                        // NE
  int2*  sdA = (int2*)(ordB + NE);              // NE int2
  float* ivA = (float*)(sdA + NE);              // NE
  int2*  sdB = (int2*)(ivA + NE);               // NE int2
  float* ivB = (float*)(sdB + NE);              // NE
  float* x1o   = ivB + NE;                      // NN*H1 (x1o,x1a,x1aa contiguous)
  float* x1a   = x1o + (size_t)NN * H1;
  float* x1aa  = x1a + (size_t)NN * H1;
  float* x2oa  = x1aa + (size_t)NN * H1;        // NN*H2
  float* x2oaa = x2oa + (size_t)NN * H2;        // NN*H2
  unsigned int* xo16u = (unsigned int*)(x2oaa + (size_t)NN * H2);  // NN*FF/2 uints
  unsigned int* xa16u = xo16u + (size_t)NN * FF / 2;
  unsigned int* x116u = xa16u + (size_t)NN * FF / 2;               // 3*NN*H1/2 uints
  unsigned int* W1fu  = x116u + (size_t)3 * NN * H1 / 2;           // 266240 uints
  unsigned int* W2fu  = W1fu + 266240;                             // 66560 uints
  const unsigned short* xo16 = (const unsigned short*)xo16u;
  const unsigned short* xa16 = (const unsigned short*)xa16u;
  const unsigned short* x1o16  = (const unsigned short*)x116u;
  const unsigned short* x1a16  = x1o16 + (size_t)NN * H1;
  const unsigned short* x1aa16 = x1a16 + (size_t)NN * H1;
  unsigned short* W1f = (unsigned short*)W1fu;
  unsigned short* W2f = (unsigned short*)W2fu;
  float* smF   = (float*)sm;
  float* hacc  = smF + SM_HACC;
  float* vbuf  = smF + SM_V;

  float* outF   = (float*)d_out;
  float* o_log  = outF;
  float* o_ros  = outF + (size_t)BQ * RR;
  float* o_rosa = o_ros + (size_t)NN * 2;
  float* o_x2o  = o_rosa + (size_t)NN * 2;

  hipMemsetAsync(wsI, 0, (2 * NRp + 1024) * sizeof(int), stream);

  // prep: bf16 conversions + W fragment packing (independent of hist/sort chain)
  k_cvt2<<<(2 * NN * FF / 8 + 255) / 256, 256, 0, stream>>>(
      (const float4*)x_o, (const float4*)x_a, (uint4*)xo16u, (uint4*)xa16u, NN * FF / 8);
  k_wprep1<<<RR, 256, 0, stream>>>(W1, W1f);
  k_wprep2<<<RR, 256, 0, stream>>>(W2, W2f);

  k_hist<<<(NE + 255) / 256, 256, 0, stream>>>(ei, etA, etB, cntA, cntB, sm);
  k_prefix<<<1, 128, 0, stream>>>(sm);
  k_scatter<<<(NE + 255) / 256, 256, 0, stream>>>(etA, etB, sm, ordA, ordB);
  k_emeta<<<(NE + 255) / 256, 256, 0, stream>>>(ei, ordA, ordB, cntA, cntB,
                                                etA, etB, sdA, ivA, sdB, ivB);

  k_root1<<<(NN * H1) / 256, 256, 0, stream>>>(x_o, x_a, rt1, b1, x1o, x1aa, x1a);
  k_edge1m<2><<<RR * CPB1, 256, 0, stream>>>(sdA, ivA, sm, SM_START_A, SM_HIST_A,
                                             W1f, xo16, xa16, x1o, x1a);
  k_edge1m<1><<<RR * CPB1, 256, 0, stream>>>(sdB, ivB, sm, SM_START_B, SM_HIST_B,
                                             W1f, xo16, nullptr, x1aa, nullptr);
  k_relu_cvt<<<(3 * NN * H1 / 8 + 255) / 256, 256, 0, stream>>>(x1o, (uint4*)x116u, 3 * NN * H1 / 8);

  k_root2x3<<<(NN * H2 + 255) / 256, 256, 0, stream>>>(x1o, x1a, x1aa, rt2, b2,
                                                       o_x2o, x2oa, x2oaa);
  k_edge2m<2><<<RR * CPB2, 256, 0, stream>>>(sdA, ivA, sm, SM_START_A, SM_HIST_A,
                                             W2f, x1o16, x1a16, o_x2o, x2oa);
  k_edge2m<1><<<RR * CPB2, 256, 0, stream>>>(sdB, ivB, sm, SM_START_B, SM_HIST_B,
                                             W2f, x1aa16, nullptr, x2oaa, nullptr);

  k_colsum<<<128, 256, 0, stream>>>(o_x2o, hacc);
  k_disc<<<1, 64, 0, stream>>>(hacc, dw, vbuf);
  k_ret<<<(NN + 255) / 256, 256, 0, stream>>>(o_x2o, x2oa, x2oaa, vbuf, db, o_ros, o_rosa);
  k_cls<<<BQ, 128, 0, stream>>>(idx, x1o, o_x2o, attt, cw, cb, o_log);
}

// Round 9
// 1001.867 us; speedup vs baseline: 3.2023x; 1.0154x over previous
//
#include <hip/hip_runtime.h>

// ---- problem dims ----
#define NN 20000
#define NE 640000
#define FF 128
#define H1 64
#define H2 32
#define RR 65
#define BQ 4096
#define NR (NN*RR)

// ---- small scratch block offsets (ints within sm[1024]) ----
#define SM_HIST_A 0
#define SM_START_A 128
#define SM_CUR_A 256
#define SM_HIST_B 384
#define SM_START_B 512
#define SM_CUR_B 640
#define SM_HACC 768   // 32 floats
#define SM_V 832      // 32 floats

#define CPB1 32
#define CPB2 32

typedef __attribute__((ext_vector_type(8))) short bhalf8;   // 8 bf16 (4 VGPRs)
typedef __attribute__((ext_vector_type(4))) float f32x4;
#define MFMA16(a, b, c) __builtin_amdgcn_mfma_f32_16x16x32_bf16(a, b, c, 0, 0, 0)

__device__ __forceinline__ unsigned short f2bf(float f) {
  unsigned int u = __float_as_uint(f);
  unsigned int r = (u + 0x7fffu + ((u >> 16) & 1u)) >> 16;   // RNE
  return (unsigned short)r;
}
__device__ __forceinline__ float bf2f(unsigned short u) {
  return __uint_as_float((unsigned)u << 16);
}
// packed bf16x2 atomic add (2 values per memory-side RMW op)
__device__ __forceinline__ void atomPK(unsigned short* p, unsigned v) {
  asm volatile("global_atomic_pk_add_bf16 %0, %1, off"
               :: "v"((unsigned long long)p), "v"(v) : "memory");
}

// ===================== histogram =====================
__global__ __launch_bounds__(256) void k_hist(
    const int* __restrict__ ei, const int* __restrict__ etA, const int* __restrict__ etB,
    int* __restrict__ cntA, int* __restrict__ cntB, int* __restrict__ sm) {
  __shared__ int lh[2 * RR];
  int tid = threadIdx.x;
  for (int i = tid; i < 2 * RR; i += blockDim.x) lh[i] = 0;
  __syncthreads();
  int e = blockIdx.x * blockDim.x + tid;
  if (e < NE) {
    int dst = ei[NE + e];
    int ta = etA[e], tb = etB[e];
    atomicAdd(&cntA[dst * RR + ta], 1);
    atomicAdd(&cntB[dst * RR + tb], 1);
    atomicAdd(&lh[ta], 1);
    atomicAdd(&lh[RR + tb], 1);
  }
  __syncthreads();
  for (int i = tid; i < 2 * RR; i += blockDim.x) {
    int c = lh[i];
    if (c) atomicAdd(&sm[(i < RR) ? (SM_HIST_A + i) : (SM_HIST_B + (i - RR))], c);
  }
}

// ===================== exclusive prefix over 65 bins =====================
__global__ __launch_bounds__(128) void k_prefix(int* __restrict__ sm) {
  int w = threadIdx.x >> 6;
  if ((threadIdx.x & 63) == 0 && w < 2) {
    int hb = w ? SM_HIST_B : SM_HIST_A;
    int sb = w ? SM_START_B : SM_START_A;
    int cb = w ? SM_CUR_B : SM_CUR_A;
    int h[RR];
#pragma unroll
    for (int r = 0; r < RR; ++r) h[r] = sm[hb + r];
    int s = 0;
#pragma unroll
    for (int r = 0; r < RR; ++r) { sm[sb + r] = s; sm[cb + r] = s; s += h[r]; }
  }
}

// ===================== counting-sort scatter =====================
__global__ __launch_bounds__(256) void k_scatter(
    const int* __restrict__ etA, const int* __restrict__ etB,
    int* __restrict__ sm, int* __restrict__ ordA, int* __restrict__ ordB) {
  __shared__ int lhA[RR], lbA[RR], lhB[RR], lbB[RR];
  int tid = threadIdx.x;
  for (int i = tid; i < RR; i += blockDim.x) { lhA[i] = 0; lhB[i] = 0; }
  __syncthreads();
  int e = blockIdx.x * blockDim.x + tid;
  int ta = 0, tb = 0, ra = 0, rb = 0;
  bool valid = (e < NE);
  if (valid) {
    ta = etA[e]; tb = etB[e];
    ra = atomicAdd(&lhA[ta], 1);
    rb = atomicAdd(&lhB[tb], 1);
  }
  __syncthreads();
  for (int i = tid; i < RR; i += blockDim.x) {
    if (lhA[i]) lbA[i] = atomicAdd(&sm[SM_CUR_A + i], lhA[i]);
    if (lhB[i]) lbB[i] = atomicAdd(&sm[SM_CUR_B + i], lhB[i]);
  }
  __syncthreads();
  if (valid) { ordA[lbA[ta] + ra] = e; ordB[lbB[tb] + rb] = e; }
}

// ===================== flatten per-position edge meta (inv computed inline) ========
__global__ __launch_bounds__(256) void k_emeta(
    const int* __restrict__ ei, const int* __restrict__ ordA, const int* __restrict__ ordB,
    const int* __restrict__ cntA, const int* __restrict__ cntB,
    const int* __restrict__ etA, const int* __restrict__ etB,
    int2* __restrict__ sdA, float* __restrict__ ivA,
    int2* __restrict__ sdB, float* __restrict__ ivB) {
  int p = blockIdx.x * blockDim.x + threadIdx.x;
  if (p >= NE) return;
  {
    int e = ordA[p]; int s = ei[e], d = ei[NE + e]; int t = etA[e];
    sdA[p] = make_int2(s, d);
    ivA[p] = 1.0f / (float)cntA[(size_t)d * RR + t];
  }
  {
    int e = ordB[p]; int s = ei[e], d = ei[NE + e]; int t = etB[e];
    sdB[p] = make_int2(s, d);
    ivB[p] = 1.0f / (float)cntB[(size_t)d * RR + t];
  }
}

// ===================== fp32 -> bf16 conversion for x_o and x_a in one pass ==========
__global__ __launch_bounds__(256) void k_cvt2(const float4* __restrict__ inA,
                                              const float4* __restrict__ inB,
                                              uint4* __restrict__ outA,
                                              uint4* __restrict__ outB, int n8) {
  int i = blockIdx.x * blockDim.x + threadIdx.x;
  if (i >= 2 * n8) return;
  const float4* in = (i < n8) ? inA : inB;
  uint4* out = (i < n8) ? outA : outB;
  int j = (i < n8) ? i : i - n8;
  float4 a = in[2 * j], b = in[2 * j + 1];
  uint4 o;
  o.x = (unsigned)f2bf(a.x) | ((unsigned)f2bf(a.y) << 16);
  o.y = (unsigned)f2bf(a.z) | ((unsigned)f2bf(a.w) << 16);
  o.z = (unsigned)f2bf(b.x) | ((unsigned)f2bf(b.y) << 16);
  o.w = (unsigned)f2bf(b.z) | ((unsigned)f2bf(b.w) << 16);
  out[j] = o;
}

// ===================== in-place bf16 relu over contiguous x1 buffers ===============
__global__ __launch_bounds__(256) void k_relu16(uint4* __restrict__ a, int n4) {
  int i = blockIdx.x * blockDim.x + threadIdx.x;
  if (i >= n4) return;
  uint4 u = a[i];
  unsigned* w = (unsigned*)&u;
#pragma unroll
  for (int t = 0; t < 4; ++t) {
    unsigned lo = (w[t] & 0x8000u) ? 0u : (w[t] & 0xFFFFu);
    unsigned hi = (w[t] & 0x80000000u) ? 0u : (w[t] & 0xFFFF0000u);
    w[t] = lo | hi;
  }
  a[i] = u;
}

// ===================== W1 -> bf16 B-fragments =====================
__global__ __launch_bounds__(256) void k_wprep1(const float* __restrict__ W,
                                                unsigned short* __restrict__ Wf) {
  int r = blockIdx.x;
  int lane = threadIdx.x & 63, w = threadIdx.x >> 6;
#pragma unroll
  for (int s4 = 0; s4 < 4; ++s4) {
    int slot = w * 4 + s4;
    int ks = slot >> 2, n = slot & 3;
    int krow = ks * 32 + ((lane >> 4) << 3);
    int colo = n * 16 + (lane & 15);
    unsigned short* o = Wf + (((size_t)r * 16 + slot) * 64 + lane) * 8;
#pragma unroll
    for (int j = 0; j < 8; ++j)
      o[j] = f2bf(W[((size_t)r * FF + krow + j) * H1 + colo]);
  }
}

// ===================== W2 -> bf16 B-fragments (K=64, N=32 -> 4 slots/rel) ==========
__global__ __launch_bounds__(256) void k_wprep2(const float* __restrict__ W,
                                                unsigned short* __restrict__ Wf) {
  int r = blockIdx.x;
  int lane = threadIdx.x & 63, slot = threadIdx.x >> 6;
  int ks = slot >> 1, n = slot & 1;
  int krow = ks * 32 + ((lane >> 4) << 3);
  int colo = n * 16 + (lane & 15);
  unsigned short* o = Wf + (((size_t)r * 4 + slot) * 64 + lane) * 8;
#pragma unroll
  for (int j = 0; j < 8; ++j)
    o[j] = f2bf(W[((size_t)r * H1 + krow + j) * H2 + colo]);
}

// ===================== layer-1 root term -> bf16 accumulators =====================
__global__ __launch_bounds__(256) void k_root1(
    const float* __restrict__ xo, const float* __restrict__ xa,
    const float* __restrict__ rt, const float* __restrict__ b,
    unsigned short* __restrict__ yo, unsigned short* __restrict__ yaa,
    unsigned short* __restrict__ ya) {
  int lane = threadIdx.x & 63;
  int n = (blockIdx.x * blockDim.x + threadIdx.x) >> 6;
  if (n >= NN) return;
  const float4* xo4 = (const float4*)(xo + (size_t)n * FF);
  const float4* xa4 = (const float4*)(xa + (size_t)n * FF);
  float so = b[lane], sa = so;
#pragma unroll
  for (int j = 0; j < FF / 4; ++j) {
    float vo[4], va[4];
    *(float4*)vo = xo4[j];
    *(float4*)va = xa4[j];
#pragma unroll
    for (int t = 0; t < 4; ++t) {
      float wv = rt[(4 * j + t) * H1 + lane];
      so = fmaf(vo[t], wv, so);
      sa = fmaf(va[t], wv, sa);
    }
  }
  yo[(size_t)n * H1 + lane] = f2bf(so);
  yaa[(size_t)n * H1 + lane] = f2bf(so);
  ya[(size_t)n * H1 + lane] = f2bf(sa);
}

// ===================== layer-1 edge GEMM via MFMA, pk-bf16 scatter =================
// col-pair scatter: even lane packs (col, col+1) of its row via shfl_xor(1) and
// issues ONE global_atomic_pk_add_bf16 -> memory-side atomic ops halved vs f32.
template <int NIN>
__global__ __launch_bounds__(256, 4) void k_edge1m(
    const int2* __restrict__ sdp, const float* __restrict__ invp,
    const int* __restrict__ sm, int startOff, int histOff,
    const unsigned short* __restrict__ Wf,
    const unsigned short* __restrict__ x16A, const unsigned short* __restrict__ x16B,
    unsigned short* __restrict__ yA, unsigned short* __restrict__ yB) {
  const int r = blockIdx.x / CPB1;
  const int lane = threadIdx.x & 63;
  bhalf8 wb[16];
  {
    const bhalf8* wf = (const bhalf8*)Wf + ((size_t)r * 16) * 64 + lane;
#pragma unroll
    for (int s = 0; s < 16; ++s) wb[s] = wf[(size_t)s * 64];
  }
  const int wvid = (blockIdx.x - r * CPB1) * 4 + (threadIdx.x >> 6);
  const int stride = CPB1 * 4;
  const int s0 = sm[startOff + r];
  const int cnt = sm[histOff + r];
  const int ngroups = (cnt + 15) >> 4;
  if (wvid >= ngroups) return;
  const int cg = lane >> 4;
  const int col = lane & 15;

  int2 sdC; float ivC;
  {
    const int base = s0 + (wvid << 4);
    const int lim = cnt - (wvid << 4);
    const int off = base + ((col < lim) ? col : 0);
    sdC = sdp[off];
    ivC = (col < lim) ? invp[off] : 0.f;
  }
  for (int G = wvid; G < ngroups; G += stride) {
    const int Gn = G + stride;
    int2 sdN = sdC; float ivN = ivC;
    if (Gn < ngroups) {
      const int base = s0 + (Gn << 4);
      const int lim = cnt - (Gn << 4);
      const int off = base + ((col < lim) ? col : 0);
      sdN = sdp[off];
      ivN = (col < lim) ? invp[off] : 0.f;
    }
    const int src = sdC.x;
    const int dstv = sdC.y;
    const int row0 = cg << 2;
    const int d0 = __shfl(dstv, row0),     d1 = __shfl(dstv, row0 + 1),
              d2 = __shfl(dstv, row0 + 2), d3 = __shfl(dstv, row0 + 3);
    const float i0 = __shfl(ivC, row0),     i1 = __shfl(ivC, row0 + 1),
                i2 = __shfl(ivC, row0 + 2), i3 = __shfl(ivC, row0 + 3);

#define SCAT1(Y, CCN, NOFF)                                                     \
    {                                                                           \
      float v0 = (CCN)[0] * i0, v1 = (CCN)[1] * i1,                             \
            v2 = (CCN)[2] * i2, v3 = (CCN)[3] * i3;                             \
      float p0 = __shfl_xor(v0, 1), p1 = __shfl_xor(v1, 1),                     \
            p2 = __shfl_xor(v2, 1), p3 = __shfl_xor(v3, 1);                     \
      if (!(lane & 1)) {                                                        \
        atomPK(Y + (size_t)d0 * H1 + (NOFF) + col, (unsigned)f2bf(v0) | ((unsigned)f2bf(p0) << 16)); \
        atomPK(Y + (size_t)d1 * H1 + (NOFF) + col, (unsigned)f2bf(v1) | ((unsigned)f2bf(p1) << 16)); \
        atomPK(Y + (size_t)d2 * H1 + (NOFF) + col, (unsigned)f2bf(v2) | ((unsigned)f2bf(p2) << 16)); \
        atomPK(Y + (size_t)d3 * H1 + (NOFF) + col, (unsigned)f2bf(v3) | ((unsigned)f2bf(p3) << 16)); \
      }                                                                         \
    }

    // ---- input A ----
    {
      const bhalf8* xr = (const bhalf8*)x16A + ((size_t)src << 4);
      bhalf8 a0 = xr[cg], a1 = xr[4 + cg], a2 = xr[8 + cg], a3 = xr[12 + cg];
      f32x4 c0 = {0.f,0.f,0.f,0.f}, c1 = c0, c2 = c0, c3 = c0;
      c0 = MFMA16(a0, wb[0], c0);  c1 = MFMA16(a0, wb[1], c1);
      c2 = MFMA16(a0, wb[2], c2);  c3 = MFMA16(a0, wb[3], c3);
      c0 = MFMA16(a1, wb[4], c0);  c1 = MFMA16(a1, wb[5], c1);
      c2 = MFMA16(a1, wb[6], c2);  c3 = MFMA16(a1, wb[7], c3);
      c0 = MFMA16(a2, wb[8], c0);  c1 = MFMA16(a2, wb[9], c1);
      c2 = MFMA16(a2, wb[10], c2); c3 = MFMA16(a2, wb[11], c3);
      c0 = MFMA16(a3, wb[12], c0); c1 = MFMA16(a3, wb[13], c1);
      c2 = MFMA16(a3, wb[14], c2); c3 = MFMA16(a3, wb[15], c3);
      SCAT1(yA, c0, 0); SCAT1(yA, c1, 16); SCAT1(yA, c2, 32); SCAT1(yA, c3, 48);
    }
    // ---- input B ----
    if constexpr (NIN == 2) {
      const bhalf8* xr = (const bhalf8*)x16B + ((size_t)src << 4);
      bhalf8 a0 = xr[cg], a1 = xr[4 + cg], a2 = xr[8 + cg], a3 = xr[12 + cg];
      f32x4 c0 = {0.f,0.f,0.f,0.f}, c1 = c0, c2 = c0, c3 = c0;
      c0 = MFMA16(a0, wb[0], c0);  c1 = MFMA16(a0, wb[1], c1);
      c2 = MFMA16(a0, wb[2], c2);  c3 = MFMA16(a0, wb[3], c3);
      c0 = MFMA16(a1, wb[4], c0);  c1 = MFMA16(a1, wb[5], c1);
      c2 = MFMA16(a1, wb[6], c2);  c3 = MFMA16(a1, wb[7], c3);
      c0 = MFMA16(a2, wb[8], c0);  c1 = MFMA16(a2, wb[9], c1);
      c2 = MFMA16(a2, wb[10], c2); c3 = MFMA16(a2, wb[11], c3);
      c0 = MFMA16(a3, wb[12], c0); c1 = MFMA16(a3, wb[13], c1);
      c2 = MFMA16(a3, wb[14], c2); c3 = MFMA16(a3, wb[15], c3);
      SCAT1(yB, c0, 0); SCAT1(yB, c1, 16); SCAT1(yB, c2, 32); SCAT1(yB, c3, 48);
    }
#undef SCAT1
    sdC = sdN; ivC = ivN;
  }
}

// ===================== layer-2 root term (bf16 in, bf16 out), 3 passes fused =======
__global__ __launch_bounds__(256) void k_root2x3(
    const unsigned short* __restrict__ x1o, const unsigned short* __restrict__ x1a,
    const unsigned short* __restrict__ x1aa,
    const float* __restrict__ rt, const float* __restrict__ b,
    unsigned short* __restrict__ y0, unsigned short* __restrict__ y1,
    unsigned short* __restrict__ y2) {
  int i = blockIdx.x * blockDim.x + threadIdx.x;
  if (i >= NN * H2) return;
  int o = i & (H2 - 1);
  int n = i >> 5;
  const uint2* p0 = (const uint2*)(x1o + (size_t)n * H1);
  const uint2* p1 = (const uint2*)(x1a + (size_t)n * H1);
  const uint2* p2 = (const uint2*)(x1aa + (size_t)n * H1);
  float s0 = b[o], s1 = s0, s2 = s0;
#pragma unroll
  for (int j = 0; j < 16; ++j) {
    uint2 u0 = p0[j], u1 = p1[j], u2 = p2[j];
#pragma unroll
    for (int t = 0; t < 4; ++t) {
      unsigned w0 = (t < 2) ? u0.x : u0.y;
      unsigned w1 = (t < 2) ? u1.x : u1.y;
      unsigned w2 = (t < 2) ? u2.x : u2.y;
      int sh = (t & 1) * 16;
      float wv = rt[(4 * j + t) * H2 + o];
      s0 = fmaf(bf2f((unsigned short)(w0 >> sh)), wv, s0);
      s1 = fmaf(bf2f((unsigned short)(w1 >> sh)), wv, s1);
      s2 = fmaf(bf2f((unsigned short)(w2 >> sh)), wv, s2);
    }
  }
  y0[i] = f2bf(s0); y1[i] = f2bf(s1); y2[i] = f2bf(s2);
}

// ===================== layer-2 edge GEMM via MFMA, pk-bf16 scatter =================
template <int NIN>
__global__ __launch_bounds__(256, 4) void k_edge2m(
    const int2* __restrict__ sdp, const float* __restrict__ invp,
    const int* __restrict__ sm, int startOff, int histOff,
    const unsigned short* __restrict__ Wf,
    const unsigned short* __restrict__ x16A, const unsigned short* __restrict__ x16B,
    unsigned short* __restrict__ yA, unsigned short* __restrict__ yB) {
  const int r = blockIdx.x / CPB2;
  const int lane = threadIdx.x & 63;
  bhalf8 wb[4];
  {
    const bhalf8* wf = (const bhalf8*)Wf + ((size_t)r * 4) * 64 + lane;
#pragma unroll
    for (int s = 0; s < 4; ++s) wb[s] = wf[(size_t)s * 64];
  }
  const int wvid = (blockIdx.x - r * CPB2) * 4 + (threadIdx.x >> 6);
  const int stride = CPB2 * 4;
  const int s0 = sm[startOff + r];
  const int cnt = sm[histOff + r];
  const int ngroups = (cnt + 15) >> 4;
  if (wvid >= ngroups) return;
  const int cg = lane >> 4;
  const int col = lane & 15;

  int2 sdC; float ivC;
  {
    const int base = s0 + (wvid << 4);
    const int lim = cnt - (wvid << 4);
    const int off = base + ((col < lim) ? col : 0);
    sdC = sdp[off];
    ivC = (col < lim) ? invp[off] : 0.f;
  }
  for (int G = wvid; G < ngroups; G += stride) {
    const int Gn = G + stride;
    int2 sdN = sdC; float ivN = ivC;
    if (Gn < ngroups) {
      const int base = s0 + (Gn << 4);
      const int lim = cnt - (Gn << 4);
      const int off = base + ((col < lim) ? col : 0);
      sdN = sdp[off];
      ivN = (col < lim) ? invp[off] : 0.f;
    }
    const int src = sdC.x;
    const int dstv = sdC.y;
    const int row0 = cg << 2;
    const int d0 = __shfl(dstv, row0),     d1 = __shfl(dstv, row0 + 1),
              d2 = __shfl(dstv, row0 + 2), d3 = __shfl(dstv, row0 + 3);
    const float i0 = __shfl(ivC, row0),     i1 = __shfl(ivC, row0 + 1),
                i2 = __shfl(ivC, row0 + 2), i3 = __shfl(ivC, row0 + 3);

#define SCAT2(Y, CCN, NOFF)                                                     \
    {                                                                           \
      float v0 = (CCN)[0] * i0, v1 = (CCN)[1] * i1,                             \
            v2 = (CCN)[2] * i2, v3 = (CCN)[3] * i3;                             \
      float p0 = __shfl_xor(v0, 1), p1 = __shfl_xor(v1, 1),                     \
            p2 = __shfl_xor(v2, 1), p3 = __shfl_xor(v3, 1);                     \
      if (!(lane & 1)) {                                                        \
        atomPK(Y + (size_t)d0 * H2 + (NOFF) + col, (unsigned)f2bf(v0) | ((unsigned)f2bf(p0) << 16)); \
        atomPK(Y + (size_t)d1 * H2 + (NOFF) + col, (unsigned)f2bf(v1) | ((unsigned)f2bf(p1) << 16)); \
        atomPK(Y + (size_t)d2 * H2 + (NOFF) + col, (unsigned)f2bf(v2) | ((unsigned)f2bf(p2) << 16)); \
        atomPK(Y + (size_t)d3 * H2 + (NOFF) + col, (unsigned)f2bf(v3) | ((unsigned)f2bf(p3) << 16)); \
      }                                                                         \
    }

    {
      const bhalf8* xr = (const bhalf8*)x16A + ((size_t)src << 3);
      bhalf8 a0 = xr[cg], a1 = xr[4 + cg];
      f32x4 c0 = {0.f,0.f,0.f,0.f}, c1 = c0;
      c0 = MFMA16(a0, wb[0], c0); c1 = MFMA16(a0, wb[1], c1);
      c0 = MFMA16(a1, wb[2], c0); c1 = MFMA16(a1, wb[3], c1);
      SCAT2(yA, c0, 0); SCAT2(yA, c1, 16);
    }
    if constexpr (NIN == 2) {
      const bhalf8* xr = (const bhalf8*)x16B + ((size_t)src << 3);
      bhalf8 a0 = xr[cg], a1 = xr[4 + cg];
      f32x4 c0 = {0.f,0.f,0.f,0.f}, c1 = c0;
      c0 = MFMA16(a0, wb[0], c0); c1 = MFMA16(a0, wb[1], c1);
      c0 = MFMA16(a1, wb[2], c0); c1 = MFMA16(a1, wb[3], c1);
      SCAT2(yB, c0, 0); SCAT2(yB, c1, 16);
    }
#undef SCAT2
    sdC = sdN; ivC = ivN;
  }
}

// ===================== x2_o bf16 -> fp32 into d_out =====================
__global__ __launch_bounds__(256) void k_fin(const uint4* __restrict__ xb,
                                             float4* __restrict__ out, int n8) {
  int i = blockIdx.x * blockDim.x + threadIdx.x;
  if (i >= n8) return;
  uint4 u = xb[i];
  float4 a, b;
  a.x = bf2f((unsigned short)u.x); a.y = bf2f((unsigned short)(u.x >> 16));
  a.z = bf2f((unsigned short)u.y); a.w = bf2f((unsigned short)(u.y >> 16));
  b.x = bf2f((unsigned short)u.z); b.y = bf2f((unsigned short)(u.z >> 16));
  b.z = bf2f((unsigned short)u.w); b.w = bf2f((unsigned short)(u.w >> 16));
  out[2 * i] = a; out[2 * i + 1] = b;
}

// ===================== column sum of x2_o (fp32) -> hacc[32] =====================
__global__ __launch_bounds__(256) void k_colsum(const float* __restrict__ x2o,
                                                float* __restrict__ hacc) {
  int tid = threadIdx.x;
  int col = tid & 31;
  int rgrp = blockIdx.x * (blockDim.x >> 5) + (tid >> 5);
  int nth = gridDim.x * (blockDim.x >> 5);
  float s = 0.f;
  for (int n = rgrp; n < NN; n += nth) s += x2o[(size_t)n * H2 + col];
  unsafeAtomicAdd(&hacc[col], s);
}

// ===================== h_os = sigmoid(mean); v = disc_w @ h_os =====================
__global__ __launch_bounds__(64) void k_disc(const float* __restrict__ hacc,
                                             const float* __restrict__ dw,
                                             float* __restrict__ vout) {
  __shared__ float hos[H2];
  int t = threadIdx.x;
  if (t < H2) hos[t] = 1.0f / (1.0f + expf(-hacc[t] / (float)NN));
  __syncthreads();
  if (t < H2) {
    float s = 0.f;
#pragma unroll
    for (int k = 0; k < H2; ++k) s = fmaf(dw[t * H2 + k], hos[k], s);
    vout[t] = s;
  }
}

// ===================== ret_os / ret_os_a (bf16 x2 inputs) =====================
__global__ __launch_bounds__(256) void k_ret(
    const unsigned short* __restrict__ x2o, const unsigned short* __restrict__ x2oa,
    const unsigned short* __restrict__ x2oaa,
    const float* __restrict__ v, const float* __restrict__ db,
    float* __restrict__ ros, float* __restrict__ rosa) {
  int n = blockIdx.x * blockDim.x + threadIdx.x;
  if (n >= NN) return;
  const uint2* a2 = (const uint2*)(x2o + (size_t)n * H2);
  const uint2* b2 = (const uint2*)(x2oa + (size_t)n * H2);
  const uint2* c2 = (const uint2*)(x2oaa + (size_t)n * H2);
  const float4* v4 = (const float4*)v;
  float r0 = 0.f, r1 = 0.f, r2 = 0.f;
#pragma unroll
  for (int j = 0; j < 8; ++j) {
    uint2 ua = a2[j], ub = b2[j], uc = c2[j];
    float4 vv = v4[j];
    r0 += bf2f((unsigned short)ua.x) * vv.x + bf2f((unsigned short)(ua.x >> 16)) * vv.y
        + bf2f((unsigned short)ua.y) * vv.z + bf2f((unsigned short)(ua.y >> 16)) * vv.w;
    r1 += bf2f((unsigned short)ub.x) * vv.x + bf2f((unsigned short)(ub.x >> 16)) * vv.y
        + bf2f((unsigned short)ub.y) * vv.z + bf2f((unsigned short)(ub.y >> 16)) * vv.w;
    r2 += bf2f((unsigned short)uc.x) * vv.x + bf2f((unsigned short)(uc.x >> 16)) * vv.y
        + bf2f((unsigned short)uc.y) * vv.z + bf2f((unsigned short)(uc.y >> 16)) * vv.w;
  }
  float bb = db[0];
  ros[n * 2] = r0 + bb;  ros[n * 2 + 1] = r1 + bb;
  rosa[n * 2] = r0 + bb; rosa[n * 2 + 1] = r2 + bb;
}

// ===================== classifier (x1o bf16, x2o fp32) =====================
__global__ __launch_bounds__(128) void k_cls(
    const int* __restrict__ idx, const unsigned short* __restrict__ x1o,
    const float* __restrict__ x2o,
    const float* __restrict__ attt, const float* __restrict__ cw, const float* __restrict__ cb,
    float* __restrict__ lg) {
  int b = blockIdx.x;
  int r = threadIdx.x;
  if (r >= RR) return;
  int i1 = idx[b], i2 = idx[BQ + b];
  float a0 = attt[0], a1 = attt[1];
  float acc = cb[r];
  const uint2* q1 = (const uint2*)(x1o + (size_t)i1 * H1);
  const float4* q2 = (const float4*)(x2o + (size_t)i1 * H2);
  const uint2* q3 = (const uint2*)(x1o + (size_t)i2 * H1);
  const float4* q4 = (const float4*)(x2o + (size_t)i2 * H2);
#pragma unroll
  for (int j = 0; j < 16; ++j) {
    uint2 u = q1[j];
    float v0 = bf2f((unsigned short)u.x), v1 = bf2f((unsigned short)(u.x >> 16));
    float v2 = bf2f((unsigned short)u.y), v3 = bf2f((unsigned short)(u.y >> 16));
    acc = fmaf(a0 * v0, cw[(4 * j) * RR + r], acc);
    acc = fmaf(a0 * v1, cw[(4 * j + 1) * RR + r], acc);
    acc = fmaf(a0 * v2, cw[(4 * j + 2) * RR + r], acc);
    acc = fmaf(a0 * v3, cw[(4 * j + 3) * RR + r], acc);
  }
#pragma unroll
  for (int j = 0; j < H2 / 4; ++j) {
    float v[4]; *(float4*)v = q2[j];
#pragma unroll
    for (int t = 0; t < 4; ++t) acc = fmaf(a1 * v[t], cw[(H1 + 4 * j + t) * RR + r], acc);
  }
#pragma unroll
  for (int j = 0; j < 16; ++j) {
    uint2 u = q3[j];
    float v0 = bf2f((unsigned short)u.x), v1 = bf2f((unsigned short)(u.x >> 16));
    float v2 = bf2f((unsigned short)u.y), v3 = bf2f((unsigned short)(u.y >> 16));
    acc = fmaf(a0 * v0, cw[(96 + 4 * j) * RR + r], acc);
    acc = fmaf(a0 * v1, cw[(96 + 4 * j + 1) * RR + r], acc);
    acc = fmaf(a0 * v2, cw[(96 + 4 * j + 2) * RR + r], acc);
    acc = fmaf(a0 * v3, cw[(96 + 4 * j + 3) * RR + r], acc);
  }
#pragma unroll
  for (int j = 0; j < H2 / 4; ++j) {
    float v[4]; *(float4*)v = q4[j];
#pragma unroll
    for (int t = 0; t < 4; ++t) acc = fmaf(a1 * v[t], cw[(96 + H1 + 4 * j + t) * RR + r], acc);
  }
  lg[(size_t)b * RR + r] = acc;
}

// ===================== launch =====================
extern "C" void kernel_launch(void* const* d_in, const int* in_sizes, int n_in,
                              void* d_out, int out_size, void* d_ws, size_t ws_size,
                              hipStream_t stream) {
  const float* x_o  = (const float*)d_in[0];
  const float* x_a  = (const float*)d_in[1];
  const int*   ei   = (const int*)d_in[2];
  const int*   etA  = (const int*)d_in[3];
  const int*   etB  = (const int*)d_in[4];
  const int*   idx  = (const int*)d_in[5];
  const float* W1   = (const float*)d_in[6];
  const float* rt1  = (const float*)d_in[7];
  const float* b1   = (const float*)d_in[8];
  const float* W2   = (const float*)d_in[9];
  const float* rt2  = (const float*)d_in[10];
  const float* b2   = (const float*)d_in[11];
  const float* attt = (const float*)d_in[12];
  const float* dw   = (const float*)d_in[13];
  const float* db   = (const float*)d_in[14];
  const float* cw   = (const float*)d_in[15];
  const float* cb   = (const float*)d_in[16];

  const size_t NRp = 1300224;
  int* wsI  = (int*)d_ws;
  int* cntA = wsI;                              // NRp ints
  int* cntB = wsI + NRp;                        // NRp ints
  int* sm   = wsI + 2 * NRp;                    // 1024
  int* ordA = sm + 1024;                        // NE
  int* ordB = ordA + NE;                        // NE
  int2*  sdA = (int2*)(ordB + NE);              // NE int2
  float* ivA = (float*)(sdA + NE);              // NE
  int2*  sdB = (int2*)(ivA + NE);               // NE int2
  float* ivB = (float*)(sdB + NE);              // NE
  // bf16 region (16B-aligned: offset 7721472 ints = 30885888 B)
  unsigned short* x1o16  = (unsigned short*)(ivB + NE);      // NN*H1
  unsigned short* x1a16  = x1o16 + (size_t)NN * H1;
  unsigned short* x1aa16 = x1a16 + (size_t)NN * H1;
  unsigned short* x2ob   = x1aa16 + (size_t)NN * H1;         // NN*H2
  unsigned short* x2oab  = x2ob + (size_t)NN * H2;
  unsigned short* x2oaab = x2oab + (size_t)NN * H2;
  unsigned short* xo16   = x2oaab + (size_t)NN * H2;         // NN*FF
  unsigned short* xa16   = xo16 + (size_t)NN * FF;
  unsigned short* W1f    = xa16 + (size_t)NN * FF;           // RR*16*64*8
  unsigned short* W2f    = W1f + (size_t)RR * 16 * 64 * 8;   // RR*4*64*8
  float* smF   = (float*)sm;
  float* hacc  = smF + SM_HACC;
  float* vbuf  = smF + SM_V;

  float* outF   = (float*)d_out;
  float* o_log  = outF;
  float* o_ros  = outF + (size_t)BQ * RR;
  float* o_rosa = o_ros + (size_t)NN * 2;
  float* o_x2o  = o_rosa + (size_t)NN * 2;

  hipMemsetAsync(wsI, 0, (2 * NRp + 1024) * sizeof(int), stream);

  // prep: bf16 conversions + W fragment packing
  k_cvt2<<<(2 * NN * FF / 8 + 255) / 256, 256, 0, stream>>>(
      (const float4*)x_o, (const float4*)x_a, (uint4*)xo16, (uint4*)xa16, NN * FF / 8);
  k_wprep1<<<RR, 256, 0, stream>>>(W1, W1f);
  k_wprep2<<<RR, 256, 0, stream>>>(W2, W2f);

  k_hist<<<(NE + 255) / 256, 256, 0, stream>>>(ei, etA, etB, cntA, cntB, sm);
  k_prefix<<<1, 128, 0, stream>>>(sm);
  k_scatter<<<(NE + 255) / 256, 256, 0, stream>>>(etA, etB, sm, ordA, ordB);
  k_emeta<<<(NE + 255) / 256, 256, 0, stream>>>(ei, ordA, ordB, cntA, cntB,
                                                etA, etB, sdA, ivA, sdB, ivB);

  k_root1<<<(NN * H1) / 256, 256, 0, stream>>>(x_o, x_a, rt1, b1, x1o16, x1aa16, x1a16);
  k_edge1m<2><<<RR * CPB1, 256, 0, stream>>>(sdA, ivA, sm, SM_START_A, SM_HIST_A,
                                             W1f, xo16, xa16, x1o16, x1a16);
  k_edge1m<1><<<RR * CPB1, 256, 0, stream>>>(sdB, ivB, sm, SM_START_B, SM_HIST_B,
                                             W1f, xo16, nullptr, x1aa16, nullptr);
  k_relu16<<<(3 * NN * H1 / 8 + 255) / 256, 256, 0, stream>>>((uint4*)x1o16, 3 * NN * H1 / 8);

  k_root2x3<<<(NN * H2 + 255) / 256, 256, 0, stream>>>(x1o16, x1a16, x1aa16, rt2, b2,
                                                       x2ob, x2oab, x2oaab);
  k_edge2m<2><<<RR * CPB2, 256, 0, stream>>>(sdA, ivA, sm, SM_START_A, SM_HIST_A,
                                             W2f, x1o16, x1a16, x2ob, x2oab);
  k_edge2m<1><<<RR * CPB2, 256, 0, stream>>>(sdB, ivB, sm, SM_START_B, SM_HIST_B,
                                             W2f, x1aa16, nullptr, x2oaab, nullptr);

  k_fin<<<(NN * H2 / 8 + 255) / 256, 256, 0, stream>>>((const uint4*)x2ob,
                                                       (float4*)o_x2o, NN * H2 / 8);
  k_colsum<<<128, 256, 0, stream>>>(o_x2o, hacc);
  k_disc<<<1, 64, 0, stream>>>(hacc, dw, vbuf);
  k_ret<<<(NN + 255) / 256, 256, 0, stream>>>(x2ob, x2oab, x2oaab, vbuf, db, o_ros, o_rosa);
  k_cls<<<BQ, 128, 0, stream>>>(idx, x1o16, o_x2o, attt, cw, cb, o_log);
}